// Round 2
// baseline (16972.780 us; speedup 1.0000x reference)
//
#include <hip/hip_runtime.h>
#include <math.h>

#define NS    8
#define NNI   32
#define NCI   128
#define NHH   16
#define NWW   16
#define NCO   128
#define NFF   1152
#define NLL   256
#define LAMV  1152.0f

// ---------------------------------------------------------------- build Xu
// Xu[f][mLocal] for ONE s (X pre-offset to s). mLocal covers nCnt*256 cols,
// n = nBase + (mLocal>>8). mShift = log2(nCnt*256).
__global__ __launch_bounds__(256) void k_build_Xu(const float* __restrict__ X,
                                                  const float* __restrict__ lp,
                                                  float* __restrict__ Xu,
                                                  int nBase, int mShift) {
  unsigned idx = blockIdx.x * 256u + threadIdx.x;     // < NFF << mShift
  unsigned m = idx & ((1u << mShift) - 1u);
  unsigned f = idx >> mShift;
  unsigned n = (unsigned)nBase + (m >> 8), l = m & 255u, h = l >> 4, w = l & 15u;
  unsigned c = f / 9u, a = f - 9u * c;
  unsigned ki = a / 3u, kj = a - 3u * ki;
  int hi = (int)(h + ki) - 1, wi = (int)(w + kj) - 1;
  float v = 0.f;
  if (hi >= 0 && hi < NHH && wi >= 0 && wi < NWW)
    v = X[(((size_t)n * NCI + c) << 8) + (unsigned)(hi * NWW + wi)];
  float sp = expf(0.5f * lp[n]);
  Xu[idx] = sp * v;
}

// Bm[c][m] = sqrt_prec[n] * u[n][c][l], m = n*256+l (full 128 x 8192, once)
__global__ __launch_bounds__(256) void k_build_B(const float* __restrict__ u,
                                                 const float* __restrict__ lp,
                                                 float* __restrict__ Bm) {
  unsigned idx = blockIdx.x * 256u + threadIdx.x;     // < 1,048,576
  unsigned m = idx & 8191u;
  unsigned c = idx >> 13;
  unsigned n = m >> 8, l = m & 255u;
  float sp = expf(0.5f * lp[n]);
  Bm[idx] = sp * u[((size_t)n * NCO + c) * NLL + l];
}

// diag init: prec[s][i][i] = LAMV (after memset-0)
__global__ void k_diag_init(float* __restrict__ prec) {
  int s = blockIdx.y;
  int i = blockIdx.x * 256 + threadIdx.x;
  if (i < NFF) prec[(size_t)s * NFF * NFF + (size_t)i * NFF + i] = LAMV;
}

// ---------------------------------------------------------------- fused GEMM, atomic K-split epilogue
// blockIdx.x < 45: lower-tri 128-tile of XLX = Xu*Xu^T -> atomicAdd into prec
// blockIdx.x 45..53: 128x128 tile of XLY = Xu*Bm^T -> atomicAdd into XLY
// blockIdx.y = K-chunk (KL = kLen >> ksShift). One s per launch.
__global__ __launch_bounds__(256, 2) void k_gemm_at(const float* __restrict__ A, int lda,
                                                    const float* __restrict__ Bmat, int ldb,
                                                    float* __restrict__ prec,
                                                    float* __restrict__ XLY,
                                                    int kLen, int ksShift) {
  int KL = kLen >> ksShift;
  int kBase = blockIdx.y * KL;
  const float* Bg;
  float* Cg;
  int ldc, row0, col0;
  if (blockIdx.x < 45) {
    int idx = blockIdx.x;
    int b = 0;
    while ((b + 1) * (b + 2) / 2 <= idx) b++;
    row0 = b * 128;
    col0 = (idx - b * (b + 1) / 2) * 128;
    Bg = A; ldb = lda; Cg = prec; ldc = NFF;
  } else {
    row0 = (blockIdx.x - 45) * 128;
    col0 = 0;
    Bg = Bmat; Cg = XLY; ldc = NCO;
  }

  __shared__ float As[16][132];
  __shared__ float Bs[16][132];
  int tid = threadIdx.x;
  int tx = tid & 15, ty = tid >> 4;
  int lr = tid >> 2, lc = tid & 3;

  float acc[8][8];
#pragma unroll
  for (int i = 0; i < 8; ++i)
#pragma unroll
    for (int j = 0; j < 8; ++j) acc[i][j] = 0.f;

  for (int k0 = kBase; k0 < kBase + KL; k0 += 16) {
    float4 a0 = *(const float4*)(A + (size_t)(row0 + lr) * lda + k0 + lc * 4);
    float4 a1 = *(const float4*)(A + (size_t)(row0 + lr + 64) * lda + k0 + lc * 4);
    float4 b0 = *(const float4*)(Bg + (size_t)(col0 + lr) * ldb + k0 + lc * 4);
    float4 b1 = *(const float4*)(Bg + (size_t)(col0 + lr + 64) * ldb + k0 + lc * 4);
    __syncthreads();
    As[lc * 4 + 0][lr] = a0.x; As[lc * 4 + 1][lr] = a0.y;
    As[lc * 4 + 2][lr] = a0.z; As[lc * 4 + 3][lr] = a0.w;
    As[lc * 4 + 0][lr + 64] = a1.x; As[lc * 4 + 1][lr + 64] = a1.y;
    As[lc * 4 + 2][lr + 64] = a1.z; As[lc * 4 + 3][lr + 64] = a1.w;
    Bs[lc * 4 + 0][lr] = b0.x; Bs[lc * 4 + 1][lr] = b0.y;
    Bs[lc * 4 + 2][lr] = b0.z; Bs[lc * 4 + 3][lr] = b0.w;
    Bs[lc * 4 + 0][lr + 64] = b1.x; Bs[lc * 4 + 1][lr + 64] = b1.y;
    Bs[lc * 4 + 2][lr + 64] = b1.z; Bs[lc * 4 + 3][lr + 64] = b1.w;
    __syncthreads();
#pragma unroll
    for (int k = 0; k < 16; ++k) {
      float av[8], bv[8];
      *(float4*)&av[0] = *(const float4*)&As[k][ty * 8];
      *(float4*)&av[4] = *(const float4*)&As[k][ty * 8 + 4];
      *(float4*)&bv[0] = *(const float4*)&Bs[k][tx * 8];
      *(float4*)&bv[4] = *(const float4*)&Bs[k][tx * 8 + 4];
#pragma unroll
      for (int i = 0; i < 8; ++i)
#pragma unroll
        for (int j = 0; j < 8; ++j) acc[i][j] = fmaf(av[i], bv[j], acc[i][j]);
    }
  }
#pragma unroll
  for (int i = 0; i < 8; ++i) {
    float* crow = Cg + (size_t)(row0 + ty * 8 + i) * ldc + col0 + tx * 8;
#pragma unroll
    for (int j = 0; j < 8; ++j) atomicAdd(&crow[j], acc[i][j]);
  }
}

// ---------------------------------------------------------------- Cholesky (blocked, NB=64)
__global__ __launch_bounds__(256) void k_chol_diag(float* __restrict__ P, int p) {
  int s = blockIdx.x;
  float* Ps = P + (size_t)s * NFF * NFF;
  __shared__ float D[64][65];
  int tid = threadIdx.x;
  int pc = p * 64;
  for (int e = tid; e < 4096; e += 256)
    D[e >> 6][e & 63] = Ps[(size_t)(pc + (e >> 6)) * NFF + pc + (e & 63)];
  __syncthreads();
  for (int j = 0; j < 64; ++j) {
    float dj = sqrtf(D[j][j]);
    float inv = 1.0f / dj;
    __syncthreads();
    if (tid == 0) D[j][j] = dj;
    for (int i = j + 1 + tid; i < 64; i += 256) D[i][j] *= inv;
    __syncthreads();
    for (int i = j + 1 + tid; i < 64; i += 256) {
      float lij = D[i][j];
      for (int k = j + 1; k <= i; ++k) D[i][k] -= lij * D[k][j];
    }
    __syncthreads();
  }
  for (int e = tid; e < 4096; e += 256)
    Ps[(size_t)(pc + (e >> 6)) * NFF + pc + (e & 63)] = D[e >> 6][e & 63];
}

__global__ __launch_bounds__(64) void k_chol_panel(float* __restrict__ P, int p) {
  int s = blockIdx.y;
  int rb = p + 1 + blockIdx.x;
  float* Ps = P + (size_t)s * NFF * NFF;
  __shared__ float L11[64][65];
  __shared__ float A2[64][65];
  int tid = threadIdx.x;
  int pc = p * 64, r0 = rb * 64;
  for (int e = tid; e < 4096; e += 64) {
    L11[e >> 6][e & 63] = Ps[(size_t)(pc + (e >> 6)) * NFF + pc + (e & 63)];
    A2[e >> 6][e & 63] = Ps[(size_t)(r0 + (e >> 6)) * NFF + pc + (e & 63)];
  }
  __syncthreads();
  for (int j = 0; j < 64; ++j) {
    float v = A2[tid][j] / L11[j][j];
    A2[tid][j] = v;
    for (int k = j + 1; k < 64; ++k) A2[tid][k] -= v * L11[k][j];
  }
  __syncthreads();
  for (int e = tid; e < 4096; e += 64)
    Ps[(size_t)(r0 + (e >> 6)) * NFF + pc + (e & 63)] = A2[e >> 6][e & 63];
}

__global__ __launch_bounds__(256) void k_chol_trail(float* __restrict__ P, int p) {
  int s = blockIdx.y;
  float* Ps = P + (size_t)s * NFF * NFF;
  int idx = blockIdx.x;
  int b = 0;
  while ((b + 1) * (b + 2) / 2 <= idx) b++;
  int bi = p + 1 + b;
  int bj = p + 1 + (idx - b * (b + 1) / 2);
  int pc = p * 64;
  __shared__ float Lis[64][68];
  __shared__ float Ljs[64][68];
  int tid = threadIdx.x;
  int i0 = tid >> 2, cq = tid & 3;
#pragma unroll
  for (int it = 0; it < 4; ++it) {
    int chunk = cq + it * 4;
    float4 va = *(const float4*)&Ps[(size_t)(bi * 64 + i0) * NFF + pc + chunk * 4];
    float4 vb = *(const float4*)&Ps[(size_t)(bj * 64 + i0) * NFF + pc + chunk * 4];
    Lis[chunk * 4 + 0][i0] = va.x; Lis[chunk * 4 + 1][i0] = va.y;
    Lis[chunk * 4 + 2][i0] = va.z; Lis[chunk * 4 + 3][i0] = va.w;
    Ljs[chunk * 4 + 0][i0] = vb.x; Ljs[chunk * 4 + 1][i0] = vb.y;
    Ljs[chunk * 4 + 2][i0] = vb.z; Ljs[chunk * 4 + 3][i0] = vb.w;
  }
  __syncthreads();
  int tx = tid & 15, ty = tid >> 4;
  float acc[4][4];
#pragma unroll
  for (int i = 0; i < 4; ++i)
#pragma unroll
    for (int j = 0; j < 4; ++j) acc[i][j] = 0.f;
#pragma unroll 8
  for (int kc = 0; kc < 64; ++kc) {
    float av[4], bv[4];
    *(float4*)av = *(const float4*)&Lis[kc][ty * 4];
    *(float4*)bv = *(const float4*)&Ljs[kc][tx * 4];
#pragma unroll
    for (int i = 0; i < 4; ++i)
#pragma unroll
      for (int j = 0; j < 4; ++j) acc[i][j] = fmaf(av[i], bv[j], acc[i][j]);
  }
#pragma unroll
  for (int i = 0; i < 4; ++i) {
    float4* cp = (float4*)&Ps[(size_t)(bi * 64 + ty * 4 + i) * NFF + bj * 64 + tx * 4];
    float4 cv = *cp;
    cv.x -= acc[i][0]; cv.y -= acc[i][1]; cv.z -= acc[i][2]; cv.w -= acc[i][3];
    *cp = cv;
  }
}

// ---------------------------------------------------------------- transpose
__global__ __launch_bounds__(256) void k_transpose(const float* __restrict__ P,
                                                   float* __restrict__ LT) {
  int s = blockIdx.z;
  const float* Ps = P + (size_t)s * NFF * NFF;
  float* Ts = LT + (size_t)s * NFF * NFF;
  __shared__ float tile[32][33];
  int bx = blockIdx.x * 32, by = blockIdx.y * 32;
  int tx = threadIdx.x & 31, ty = threadIdx.x >> 5;
  for (int r = ty; r < 32; r += 8) tile[r][tx] = Ps[(size_t)(by + r) * NFF + bx + tx];
  __syncthreads();
  for (int r = ty; r < 32; r += 8) Ts[(size_t)(bx + r) * NFF + by + tx] = tile[tx][r];
}

// ---------------------------------------------------------------- triangular solves
__global__ __launch_bounds__(256) void k_fwd_solve(const float* __restrict__ L,
                                                   const float* __restrict__ B,
                                                   float* __restrict__ Xo) {
  int s = blockIdx.y, cg = blockIdx.x;
  const float* Ls = L + (size_t)s * NFF * NFF;
  const float* Bsrc = B + (size_t)s * NFF * NCO + cg * 8;
  float* Odst = Xo + (size_t)s * NFF * NCO + cg * 8;
  __shared__ float xs[NFF][8];
  __shared__ float red[32][9];
  int c = threadIdx.x & 7, q = threadIdx.x >> 3;
  for (int i = 0; i < NFF; ++i) {
    const float* Lrow = Ls + (size_t)i * NFF;
    float acc = 0.f;
    for (int j = q; j < i; j += 32) acc = fmaf(Lrow[j], xs[j][c], acc);
    red[q][c] = acc;
    __syncthreads();
    if (threadIdx.x < 8) {
      float dot = 0.f;
      for (int k = 0; k < 32; ++k) dot += red[k][c];
      float x = (Bsrc[(size_t)i * NCO + c] - dot) / Lrow[i];
      xs[i][c] = x;
      Odst[(size_t)i * NCO + c] = x;
    }
    __syncthreads();
  }
}

__global__ __launch_bounds__(256) void k_bwd_solve(const float* __restrict__ LT,
                                                   const float* __restrict__ B1,
                                                   float* __restrict__ O1,
                                                   const float* __restrict__ B2,
                                                   float* __restrict__ O2) {
  int s = blockIdx.y, cg = blockIdx.x;
  const float* Bsrc;
  float* Odst;
  int coff;
  if (cg < 16) { Bsrc = B1; Odst = O1; coff = cg * 8; }
  else { Bsrc = B2; Odst = O2; coff = (cg - 16) * 8; }
  const float* Ls = LT + (size_t)s * NFF * NFF;
  Bsrc += (size_t)s * NFF * NCO + coff;
  Odst += (size_t)s * NFF * NCO + coff;
  __shared__ float xs[NFF][8];
  __shared__ float red[32][9];
  int c = threadIdx.x & 7, q = threadIdx.x >> 3;
  for (int i = NFF - 1; i >= 0; --i) {
    const float* Lrow = Ls + (size_t)i * NFF;
    float acc = 0.f;
    for (int j = i + 1 + q; j < NFF; j += 32) acc = fmaf(Lrow[j], xs[j][c], acc);
    red[q][c] = acc;
    __syncthreads();
    if (threadIdx.x < 8) {
      float dot = 0.f;
      for (int k = 0; k < 32; ++k) dot += red[k][c];
      float x = (Bsrc[(size_t)i * NCO + c] - dot) / Lrow[i];
      xs[i][c] = x;
      Odst[(size_t)i * NCO + c] = x;
    }
    __syncthreads();
  }
}

// ---------------------------------------------------------------- epilogue
__global__ __launch_bounds__(256) void k_logdet(const float* __restrict__ P,
                                                float* __restrict__ accum) {
  int s = blockIdx.x;
  float part = 0.f;
  for (int i = threadIdx.x; i < NFF; i += 256)
    part += logf(P[(size_t)s * NFF * NFF + (size_t)i * NFF + i]);
  __shared__ float r[256];
  r[threadIdx.x] = part;
  __syncthreads();
  for (int off = 128; off > 0; off >>= 1) {
    if (threadIdx.x < off) r[threadIdx.x] += r[threadIdx.x + off];
    __syncthreads();
  }
  if (threadIdx.x == 0) {
    accum[s * 4 + 0] = 0.f;
    accum[s * 4 + 1] = 0.f;
    accum[s * 4 + 2] = 2.f * r[0];
  }
}

__global__ __launch_bounds__(256) void k_sample(const float* __restrict__ mu,
                                                const float* __restrict__ dW,
                                                const float* __restrict__ Z,
                                                float* __restrict__ sout,
                                                float* __restrict__ accum) {
  int s = blockIdx.y;
  int base = blockIdx.x * 2048;
  size_t so = (size_t)s * NFF * NCO;
  float s2 = 0.f, z2 = 0.f;
  for (int e = base + threadIdx.x; e < base + 2048; e += 256) {
    float v = mu[so + e] + dW[so + e];
    float z = Z[so + e];
    int f = e >> 7, c = e & 127;
    sout[(size_t)s * NCO * NFF + (size_t)c * NFF + f] = v;
    s2 = fmaf(v, v, s2);
    z2 = fmaf(z, z, z2);
  }
  __shared__ float r1[256], r2[256];
  r1[threadIdx.x] = s2;
  r2[threadIdx.x] = z2;
  __syncthreads();
  for (int off = 128; off > 0; off >>= 1) {
    if (threadIdx.x < off) {
      r1[threadIdx.x] += r1[threadIdx.x + off];
      r2[threadIdx.x] += r2[threadIdx.x + off];
    }
    __syncthreads();
  }
  if (threadIdx.x == 0) {
    atomicAdd(&accum[s * 4 + 0], r1[0]);
    atomicAdd(&accum[s * 4 + 1], r2[0]);
  }
}

__global__ void k_final(const float* __restrict__ accum, float* __restrict__ outLogpq) {
  int s = threadIdx.x;
  if (s < NS) {
    float s2 = accum[s * 4 + 0];
    float z2 = accum[s * 4 + 1];
    float ld = accum[s * 4 + 2];
    float logP = -0.5f * LAMV * s2 + 0.5f * (float)(NCO * NFF) * logf(LAMV);
    float logQ = -0.5f * z2 + 0.5f * (float)NCO * ld;
    outLogpq[s] = logP - logQ;
  }
}

// ---------------------------------------------------------------- launch
extern "C" void kernel_launch(void* const* d_in, const int* in_sizes, int n_in,
                              void* d_out, int out_size, void* d_ws, size_t ws_size,
                              hipStream_t stream) {
  const float* X = (const float*)d_in[0];
  const float* u = (const float*)d_in[1];
  const float* lp = (const float*)d_in[2];
  const float* Z = (const float*)d_in[3];
  float* out = (float*)d_out;

  const size_t XU_A = 37748736;   // 1152*8192*4
  const size_t XU_C = 9437184;    // 1152*2048*4
  const size_t FF4 = 5308416;     // 1152*1152*4
  const size_t FC4 = 589824;      // 1152*128*4
  const size_t BM4 = 4194304;     // 128*8192*4
  const size_t FC = 147456;       // elems
  const size_t FF = 1327104;      // elems
  const size_t XSTR = 1048576;    // X elems per s

  size_t needA = BM4 + 8 * FF4 + ((XU_A > 8 * FF4) ? XU_A : 8 * FF4) + 4 * 8 * FC4 + 4096;
  size_t needB = BM4 + XU_A + FF4 + 4 * FC4 + 4096;

  char* ws = (char*)d_ws;

  if (ws_size >= needA) {
    // -------- path A: per-s build+GEMM, batched chol/solves --------
    size_t off = 0;
    float* Bm = (float*)(ws + off);   off += BM4;
    float* Xu = (float*)(ws + off);   // union with LT
    float* LTm = Xu;                  off += (XU_A > 8 * FF4) ? XU_A : 8 * FF4;
    float* prec = (float*)(ws + off); off += 8 * FF4;
    float* XLY = (float*)(ws + off);  off += 8 * FC4;
    float* t1 = (float*)(ws + off);   off += 8 * FC4;
    float* muB = (float*)(ws + off);  off += 8 * FC4;
    float* dWB = (float*)(ws + off);  off += 8 * FC4;
    float* accum = (float*)(ws + off);

    k_build_B<<<4096, 256, 0, stream>>>(u, lp, Bm);
    hipMemsetAsync(prec, 0, 8 * FF4, stream);
    hipMemsetAsync(XLY, 0, 8 * FC4, stream);
    k_diag_init<<<dim3(5, 8), 256, 0, stream>>>(prec);

    for (int sg = 0; sg < NS; ++sg) {
      k_build_Xu<<<36864, 256, 0, stream>>>(X + (size_t)sg * XSTR, lp, Xu, 0, 13);
      k_gemm_at<<<dim3(54, 8), 256, 0, stream>>>(Xu, 8192, Bm, 8192,
                                                 prec + (size_t)sg * FF,
                                                 XLY + (size_t)sg * FC, 8192, 3);
    }
    for (int p = 0; p < 18; ++p) {
      k_chol_diag<<<8, 256, 0, stream>>>(prec, p);
      if (p < 17) {
        int T = 17 - p;
        k_chol_panel<<<dim3(T, 8), 64, 0, stream>>>(prec, p);
        k_chol_trail<<<dim3(T * (T + 1) / 2, 8), 256, 0, stream>>>(prec, p);
      }
    }
    k_transpose<<<dim3(36, 36, 8), 256, 0, stream>>>(prec, LTm);
    k_fwd_solve<<<dim3(16, 8), 256, 0, stream>>>(prec, XLY, t1);
    k_bwd_solve<<<dim3(32, 8), 256, 0, stream>>>(LTm, t1, muB, Z, dWB);
    k_logdet<<<8, 256, 0, stream>>>(prec, accum);
    k_sample<<<dim3(72, 8), 256, 0, stream>>>(muB, dWB, Z, out, accum);
    k_final<<<1, 64, 0, stream>>>(accum, out + (size_t)NS * FC);
  } else {
    // -------- path B/C: fully per-s (C also chunks n) --------
    int nChunk = (ws_size >= needB) ? 1 : 4;
    int mShift = (nChunk == 1) ? 13 : 11;
    size_t xuSz = (nChunk == 1) ? XU_A : XU_C;

    size_t off = 0;
    float* Bm = (float*)(ws + off);    off += BM4;
    float* Xu = (float*)(ws + off);    // union with per-s LT
    float* LTm = Xu;                   off += xuSz;
    float* prec1 = (float*)(ws + off); off += FF4;
    float* XLY1 = (float*)(ws + off);  off += FC4;
    float* t1b = (float*)(ws + off);   off += FC4;
    float* mu1 = (float*)(ws + off);   off += FC4;
    float* dW1 = (float*)(ws + off);   off += FC4;
    float* accum = (float*)(ws + off);

    k_build_B<<<4096, 256, 0, stream>>>(u, lp, Bm);

    for (int sg = 0; sg < NS; ++sg) {
      hipMemsetAsync(prec1, 0, FF4, stream);
      hipMemsetAsync(XLY1, 0, FC4, stream);
      k_diag_init<<<dim3(5, 1), 256, 0, stream>>>(prec1);
      for (int nb = 0; nb < nChunk; ++nb) {
        int nCnt = 32 / nChunk;
        k_build_Xu<<<(1152 << mShift) / 256, 256, 0, stream>>>(
            X + (size_t)sg * XSTR, lp, Xu, nb * nCnt, mShift);
        k_gemm_at<<<dim3(54, 8), 256, 0, stream>>>(
            Xu, 1 << mShift, Bm + (size_t)nb * (1 << mShift), 8192,
            prec1, XLY1, 1 << mShift, 3);
      }
      for (int p = 0; p < 18; ++p) {
        k_chol_diag<<<1, 256, 0, stream>>>(prec1, p);
        if (p < 17) {
          int T = 17 - p;
          k_chol_panel<<<dim3(T, 1), 64, 0, stream>>>(prec1, p);
          k_chol_trail<<<dim3(T * (T + 1) / 2, 1), 256, 0, stream>>>(prec1, p);
        }
      }
      k_transpose<<<dim3(36, 36, 1), 256, 0, stream>>>(prec1, LTm);
      k_fwd_solve<<<dim3(16, 1), 256, 0, stream>>>(prec1, XLY1, t1b);
      k_bwd_solve<<<dim3(32, 1), 256, 0, stream>>>(LTm, t1b, mu1, Z + (size_t)sg * FC, dW1);
      k_logdet<<<1, 256, 0, stream>>>(prec1, accum + sg * 4);
      k_sample<<<dim3(72, 1), 256, 0, stream>>>(mu1, dW1, Z + (size_t)sg * FC,
                                                out + (size_t)sg * FC, accum + sg * 4);
    }
    k_final<<<1, 64, 0, stream>>>(accum, out + (size_t)NS * FC);
  }
}

// Round 3
// 8689.313 us; speedup vs baseline: 1.9533x; 1.9533x over previous
//
#include <hip/hip_runtime.h>
#include <hip/hip_bf16.h>
#include <math.h>

#define NS    8
#define NNI   32
#define NCI   128
#define NHH   16
#define NWW   16
#define NCO   128
#define NFF   1152
#define NLL   256
#define LAMV  1152.0f

typedef short s8v __attribute__((ext_vector_type(8)));
typedef float f4v __attribute__((ext_vector_type(4)));

#define AS1 __attribute__((address_space(1)))
#define AS3 __attribute__((address_space(3)))

// ---------------------------------------------------------------- build Xu (bf16) for one s
// Xu[f][m], f=c*9+ki*3+kj, m=n*256+h*16+w
__global__ __launch_bounds__(256) void k_build_Xu(const float* __restrict__ X,
                                                  const float* __restrict__ lp,
                                                  unsigned short* __restrict__ Xu) {
  unsigned idx = blockIdx.x * 256u + threadIdx.x;   // < 1152*8192
  unsigned m = idx & 8191u;
  unsigned f = idx >> 13;
  unsigned n = m >> 8, l = m & 255u, h = l >> 4, w = l & 15u;
  unsigned c = f / 9u, a = f - 9u * c;
  unsigned ki = a / 3u, kj = a - 3u * ki;
  int hi = (int)(h + ki) - 1, wi = (int)(w + kj) - 1;
  float v = 0.f;
  if (hi >= 0 && hi < NHH && wi >= 0 && wi < NWW)
    v = X[(((size_t)n * NCI + c) << 8) + (unsigned)(hi * NWW + wi)];
  float sp = expf(0.5f * lp[n]);
  __hip_bfloat16 hv = __float2bfloat16(sp * v);
  Xu[idx] = *(unsigned short*)&hv;
}

// Bm[c][m] = sqrt_prec[n] * u[n][c][l]  (bf16, 128 x 8192)
__global__ __launch_bounds__(256) void k_build_B(const float* __restrict__ u,
                                                 const float* __restrict__ lp,
                                                 unsigned short* __restrict__ Bm) {
  unsigned idx = blockIdx.x * 256u + threadIdx.x;   // < 1,048,576
  unsigned m = idx & 8191u;
  unsigned c = idx >> 13;
  unsigned n = m >> 8, l = m & 255u;
  float sp = expf(0.5f * lp[n]);
  __hip_bfloat16 hv = __float2bfloat16(sp * u[((size_t)n * NCO + c) * NLL + l]);
  Bm[idx] = *(unsigned short*)&hv;
}

__global__ void k_diag_init(float* __restrict__ prec) {
  int s = blockIdx.y;
  int i = blockIdx.x * 256 + threadIdx.x;
  if (i < NFF) prec[(size_t)s * NFF * NFF + (size_t)i * NFF + i] = LAMV;
}

// ---------------------------------------------------------------- MFMA bf16 GEMM (one s per launch)
// bx<45: lower-tri 128-tile of XLX = Xu*Xu^T -> atomicAdd prec
// bx 45..53: 128x128 tile of XLY = Xu*Bm^T -> atomicAdd XLY
// by = K-chunk of 1024 (8 chunks). LDS tiles 128x64 bf16, XOR-swizzled 16B chunks.
__global__ __launch_bounds__(256) void k_mfma(const unsigned short* __restrict__ Xu,
                                              const unsigned short* __restrict__ Bm,
                                              float* __restrict__ prec,
                                              float* __restrict__ XLY) {
  __shared__ unsigned short As[8192];
  __shared__ unsigned short Bs[8192];
  int bx = blockIdx.x;
  int row0, col0;
  const unsigned short* Ag;
  const unsigned short* Bg;
  bool isXLX;
  if (bx < 45) {
    int b = 0;
    while ((b + 1) * (b + 2) / 2 <= bx) b++;
    row0 = b * 128;
    col0 = (bx - b * (b + 1) / 2) * 128;
    Bg = Xu + (size_t)col0 * 8192;
    isXLX = true;
  } else {
    row0 = (bx - 45) * 128;
    col0 = 0;
    Bg = Bm;
    isXLX = false;
  }
  Ag = Xu + (size_t)row0 * 8192;

  int t = threadIdx.x;
  int lane = t & 63, w = t >> 6;
  int wm = w & 1, wn = w >> 1;
  int n16 = lane & 15, q = lane >> 4;
  int srow = lane >> 3, sch = lane & 7;

  f4v acc[4][4];
#pragma unroll
  for (int i = 0; i < 4; ++i)
#pragma unroll
    for (int j = 0; j < 4; ++j) acc[i][j] = (f4v)0.f;

  int kBase = blockIdx.y * 1024;
  for (int k0 = kBase; k0 < kBase + 1024; k0 += 64) {
    __syncthreads();
#pragma unroll
    for (int it = 0; it < 4; ++it) {
      int rA = (w * 4 + it) * 8 + srow;       // 0..127
      int cA = (sch - rA) & 7;                // source chunk for swizzled slot
      const unsigned short* gpa = Ag + (size_t)rA * 8192 + k0 + cA * 8;
      const unsigned short* gpb = Bg + (size_t)rA * 8192 + k0 + cA * 8;
      __builtin_amdgcn_global_load_lds((AS1 const void*)gpa,
                                       (AS3 void*)&As[(w * 4 + it) * 512], 16, 0, 0);
      __builtin_amdgcn_global_load_lds((AS1 const void*)gpb,
                                       (AS3 void*)&Bs[(w * 4 + it) * 512], 16, 0, 0);
    }
    __syncthreads();
#pragma unroll
    for (int kk = 0; kk < 2; ++kk) {
      s8v af[4], bf[4];
#pragma unroll
      for (int im = 0; im < 4; ++im) {
        int r = wm * 64 + im * 16 + n16;
        int slot = ((kk * 4 + q) + r) & 7;
        af[im] = *(const s8v*)&As[r * 64 + slot * 8];
      }
#pragma unroll
      for (int in = 0; in < 4; ++in) {
        int r = wn * 64 + in * 16 + n16;
        int slot = ((kk * 4 + q) + r) & 7;
        bf[in] = *(const s8v*)&Bs[r * 64 + slot * 8];
      }
#pragma unroll
      for (int im = 0; im < 4; ++im)
#pragma unroll
        for (int in = 0; in < 4; ++in)
          acc[im][in] = __builtin_amdgcn_mfma_f32_16x16x32_bf16(af[im], bf[in], acc[im][in], 0, 0, 0);
    }
  }

  if (isXLX) {
#pragma unroll
    for (int im = 0; im < 4; ++im)
#pragma unroll
      for (int in = 0; in < 4; ++in) {
        int gr = row0 + wm * 64 + im * 16 + q * 4;
        int gc = col0 + wn * 64 + in * 16 + n16;
#pragma unroll
        for (int tt = 0; tt < 4; ++tt)
          atomicAdd(&prec[(size_t)(gr + tt) * NFF + gc], acc[im][in][tt]);
      }
  } else {
#pragma unroll
    for (int im = 0; im < 4; ++im)
#pragma unroll
      for (int in = 0; in < 4; ++in) {
        int gr = row0 + wm * 64 + im * 16 + q * 4;
        int gc = wn * 64 + in * 16 + n16;
#pragma unroll
        for (int tt = 0; tt < 4; ++tt)
          atomicAdd(&XLY[(size_t)(gr + tt) * NCO + gc], acc[im][in][tt]);
      }
  }
}

// ---------------------------------------------------------------- Cholesky NB=128
__global__ __launch_bounds__(256) void k_chol_diag(float* __restrict__ P, int p) {
  int s = blockIdx.x;
  float* Ps = P + (size_t)s * NFF * NFF;
  __shared__ float D[128][129];
  int t = threadIdx.x;
  int pc = p * 128;
  for (int e = t; e < 16384; e += 256)
    D[e >> 7][e & 127] = Ps[(size_t)(pc + (e >> 7)) * NFF + pc + (e & 127)];
  int i2 = t & 127, kh = t >> 7;
  for (int j = 0; j < 128; ++j) {
    __syncthreads();                 // prior rank-1 (or load) visible
    float dv = D[j][j];
    float dj = sqrtf(dv);
    float inv = 1.0f / dj;
    __syncthreads();                 // everyone read dv
    if (t == 0) D[j][j] = dj;
    for (int i = j + 1 + t; i < 128; i += 256) D[i][j] *= inv;
    __syncthreads();                 // column j final
    int i = j + 1 + i2;
    if (i < 128) {
      float lij = D[i][j];
      for (int k = j + 1 + kh; k <= i; k += 2) D[i][k] = fmaf(-lij, D[k][j], D[i][k]);
    }
  }
  __syncthreads();
  for (int e = t; e < 16384; e += 256) {
    int r = e >> 7, cc = e & 127;
    if (cc <= r) Ps[(size_t)(pc + r) * NFF + pc + cc] = D[r][cc];
  }
}

// panel: L21 = A21 * L11^{-T}; one 128-row block per workgroup; thread t owns row t (no syncs in sweep)
__global__ __launch_bounds__(128) void k_chol_panel(float* __restrict__ P, int p) {
  int s = blockIdx.y;
  float* Ps = P + (size_t)s * NFF * NFF;
  __shared__ float L11[128][129];
  __shared__ float A2[128][129];
  int t = threadIdx.x;
  int pc = p * 128, r0 = (p + 1 + (int)blockIdx.x) * 128;
  for (int e = t; e < 16384; e += 128) {
    L11[e >> 7][e & 127] = Ps[(size_t)(pc + (e >> 7)) * NFF + pc + (e & 127)];
    A2[e >> 7][e & 127] = Ps[(size_t)(r0 + (e >> 7)) * NFF + pc + (e & 127)];
  }
  __syncthreads();
  for (int j = 0; j < 128; ++j) {
    float v = A2[t][j] / L11[j][j];
    A2[t][j] = v;
    for (int k = j + 1; k < 128; ++k) A2[t][k] = fmaf(-v, L11[k][j], A2[t][k]);
  }
  __syncthreads();
  for (int e = t; e < 16384; e += 128)
    Ps[(size_t)(r0 + (e >> 7)) * NFF + pc + (e & 127)] = A2[e >> 7][e & 127];
}

// trailing: A[bi][bj] -= L21[bi] * L21[bj]^T  (128x128 tile, K=128)
__global__ __launch_bounds__(256) void k_chol_trail(float* __restrict__ P, int p) {
  int s = blockIdx.y;
  float* Ps = P + (size_t)s * NFF * NFF;
  int idx = blockIdx.x;
  int b = 0;
  while ((b + 1) * (b + 2) / 2 <= idx) b++;
  int bi = p + 1 + b, bj = p + 1 + (idx - b * (b + 1) / 2);
  int pc = p * 128;
  const float* Ag = Ps + (size_t)(bi * 128) * NFF + pc;
  const float* Bg = Ps + (size_t)(bj * 128) * NFF + pc;
  __shared__ float As_[16][132];
  __shared__ float Bs_[16][132];
  int tid = threadIdx.x;
  int tx = tid & 15, ty = tid >> 4;
  int lr = tid >> 2, lc = tid & 3;
  float acc[8][8];
#pragma unroll
  for (int i = 0; i < 8; ++i)
#pragma unroll
    for (int j = 0; j < 8; ++j) acc[i][j] = 0.f;
  for (int k0 = 0; k0 < 128; k0 += 16) {
    float4 a0 = *(const float4*)(Ag + (size_t)lr * NFF + k0 + lc * 4);
    float4 a1 = *(const float4*)(Ag + (size_t)(lr + 64) * NFF + k0 + lc * 4);
    float4 b0 = *(const float4*)(Bg + (size_t)lr * NFF + k0 + lc * 4);
    float4 b1 = *(const float4*)(Bg + (size_t)(lr + 64) * NFF + k0 + lc * 4);
    __syncthreads();
    As_[lc * 4 + 0][lr] = a0.x; As_[lc * 4 + 1][lr] = a0.y;
    As_[lc * 4 + 2][lr] = a0.z; As_[lc * 4 + 3][lr] = a0.w;
    As_[lc * 4 + 0][lr + 64] = a1.x; As_[lc * 4 + 1][lr + 64] = a1.y;
    As_[lc * 4 + 2][lr + 64] = a1.z; As_[lc * 4 + 3][lr + 64] = a1.w;
    Bs_[lc * 4 + 0][lr] = b0.x; Bs_[lc * 4 + 1][lr] = b0.y;
    Bs_[lc * 4 + 2][lr] = b0.z; Bs_[lc * 4 + 3][lr] = b0.w;
    Bs_[lc * 4 + 0][lr + 64] = b1.x; Bs_[lc * 4 + 1][lr + 64] = b1.y;
    Bs_[lc * 4 + 2][lr + 64] = b1.z; Bs_[lc * 4 + 3][lr + 64] = b1.w;
    __syncthreads();
#pragma unroll
    for (int k = 0; k < 16; ++k) {
      float av[8], bv[8];
      *(float4*)&av[0] = *(const float4*)&As_[k][ty * 8];
      *(float4*)&av[4] = *(const float4*)&As_[k][ty * 8 + 4];
      *(float4*)&bv[0] = *(const float4*)&Bs_[k][tx * 8];
      *(float4*)&bv[4] = *(const float4*)&Bs_[k][tx * 8 + 4];
#pragma unroll
      for (int i = 0; i < 8; ++i)
#pragma unroll
        for (int j = 0; j < 8; ++j) acc[i][j] = fmaf(av[i], bv[j], acc[i][j]);
    }
  }
#pragma unroll
  for (int i = 0; i < 8; ++i) {
    float* crow = Ps + (size_t)(bi * 128 + ty * 8 + i) * NFF + bj * 128 + tx * 8;
    float4 c0 = *(float4*)crow;
    float4 c1 = *(float4*)(crow + 4);
    c0.x -= acc[i][0]; c0.y -= acc[i][1]; c0.z -= acc[i][2]; c0.w -= acc[i][3];
    c1.x -= acc[i][4]; c1.y -= acc[i][5]; c1.z -= acc[i][6]; c1.w -= acc[i][7];
    *(float4*)crow = c0;
    *(float4*)(crow + 4) = c1;
  }
}

// ---------------------------------------------------------------- transpose
__global__ __launch_bounds__(256) void k_transpose(const float* __restrict__ P,
                                                   float* __restrict__ LT) {
  int s = blockIdx.z;
  const float* Ps = P + (size_t)s * NFF * NFF;
  float* Ts = LT + (size_t)s * NFF * NFF;
  __shared__ float tile[32][33];
  int bx = blockIdx.x * 32, by = blockIdx.y * 32;
  int tx = threadIdx.x & 31, ty = threadIdx.x >> 5;
  for (int r = ty; r < 32; r += 8) tile[r][tx] = Ps[(size_t)(by + r) * NFF + bx + tx];
  __syncthreads();
  for (int r = ty; r < 32; r += 8) Ts[(size_t)(bx + r) * NFF + by + tx] = tile[tx][r];
}

// ---------------------------------------------------------------- blocked triangular solves
// forward: L x = b. block = (s, 16 cols). xs history in LDS; serial diag phase has no syncs.
__global__ __launch_bounds__(256) void k_fwd_solve(const float* __restrict__ L,
                                                   const float* __restrict__ B,
                                                   float* __restrict__ O) {
  int s = blockIdx.y, cg = blockIdx.x;
  const float* Ls = L + (size_t)s * NFF * NFF;
  const float* Bsrc = B + (size_t)s * NFF * NCO + cg * 16;
  float* Odst = O + (size_t)s * NFF * NCO + cg * 16;
  __shared__ float xs[NFF][16];
  __shared__ float Ld[64][65];
  __shared__ float Lp[64][65];
  __shared__ float U[64][17];
  int t = threadIdx.x, c = t & 15, rt = t >> 4;
  for (int rb = 0; rb < 18; ++rb) {
    int r0 = rb * 64;
    float a0 = 0.f, a1 = 0.f, a2 = 0.f, a3 = 0.f;
    for (int kb = 0; kb < rb; ++kb) {
      __syncthreads();
      for (int e = t; e < 4096; e += 256)
        Lp[e >> 6][e & 63] = Ls[(size_t)(r0 + (e >> 6)) * NFF + kb * 64 + (e & 63)];
      __syncthreads();
#pragma unroll 4
      for (int k = 0; k < 64; ++k) {
        float xv = xs[kb * 64 + k][c];
        a0 = fmaf(Lp[rt * 4 + 0][k], xv, a0);
        a1 = fmaf(Lp[rt * 4 + 1][k], xv, a1);
        a2 = fmaf(Lp[rt * 4 + 2][k], xv, a2);
        a3 = fmaf(Lp[rt * 4 + 3][k], xv, a3);
      }
    }
    __syncthreads();
    for (int e = t; e < 4096; e += 256)
      Ld[e >> 6][e & 63] = Ls[(size_t)(r0 + (e >> 6)) * NFF + r0 + (e & 63)];
    U[rt * 4 + 0][c] = Bsrc[(size_t)(r0 + rt * 4 + 0) * NCO + c] - a0;
    U[rt * 4 + 1][c] = Bsrc[(size_t)(r0 + rt * 4 + 1) * NCO + c] - a1;
    U[rt * 4 + 2][c] = Bsrc[(size_t)(r0 + rt * 4 + 2) * NCO + c] - a2;
    U[rt * 4 + 3][c] = Bsrc[(size_t)(r0 + rt * 4 + 3) * NCO + c] - a3;
    __syncthreads();
    if (t < 16) {
      for (int j = 0; j < 64; ++j) {
        float x = U[j][t];
        for (int j2 = 0; j2 < j; ++j2) x = fmaf(-Ld[j][j2], xs[r0 + j2][t], x);
        x /= Ld[j][j];
        xs[r0 + j][t] = x;
        Odst[(size_t)(r0 + j) * NCO + t] = x;
      }
    }
    __syncthreads();
  }
}

// backward: L^T x = b via LT (upper). g<8 -> (B1,O1), else (B2,O2)
__global__ __launch_bounds__(256) void k_bwd_solve(const float* __restrict__ LT,
                                                   const float* __restrict__ B1,
                                                   float* __restrict__ O1,
                                                   const float* __restrict__ B2,
                                                   float* __restrict__ O2) {
  int s = blockIdx.y, g = blockIdx.x;
  int c0 = (g & 7) * 16;
  const float* Bsrc;
  float* Odst;
  if (g < 8) { Bsrc = B1; Odst = O1; } else { Bsrc = B2; Odst = O2; }
  const float* Ls = LT + (size_t)s * NFF * NFF;
  Bsrc += (size_t)s * NFF * NCO + c0;
  Odst += (size_t)s * NFF * NCO + c0;
  __shared__ float xs[NFF][16];
  __shared__ float Ld[64][65];
  __shared__ float Lp[64][65];
  __shared__ float U[64][17];
  int t = threadIdx.x, c = t & 15, rt = t >> 4;
  for (int rb = 17; rb >= 0; --rb) {
    int r0 = rb * 64;
    float a0 = 0.f, a1 = 0.f, a2 = 0.f, a3 = 0.f;
    for (int kb = rb + 1; kb < 18; ++kb) {
      __syncthreads();
      for (int e = t; e < 4096; e += 256)
        Lp[e >> 6][e & 63] = Ls[(size_t)(r0 + (e >> 6)) * NFF + kb * 64 + (e & 63)];
      __syncthreads();
#pragma unroll 4
      for (int k = 0; k < 64; ++k) {
        float xv = xs[kb * 64 + k][c];
        a0 = fmaf(Lp[rt * 4 + 0][k], xv, a0);
        a1 = fmaf(Lp[rt * 4 + 1][k], xv, a1);
        a2 = fmaf(Lp[rt * 4 + 2][k], xv, a2);
        a3 = fmaf(Lp[rt * 4 + 3][k], xv, a3);
      }
    }
    __syncthreads();
    for (int e = t; e < 4096; e += 256)
      Ld[e >> 6][e & 63] = Ls[(size_t)(r0 + (e >> 6)) * NFF + r0 + (e & 63)];
    U[rt * 4 + 0][c] = Bsrc[(size_t)(r0 + rt * 4 + 0) * NCO + c] - a0;
    U[rt * 4 + 1][c] = Bsrc[(size_t)(r0 + rt * 4 + 1) * NCO + c] - a1;
    U[rt * 4 + 2][c] = Bsrc[(size_t)(r0 + rt * 4 + 2) * NCO + c] - a2;
    U[rt * 4 + 3][c] = Bsrc[(size_t)(r0 + rt * 4 + 3) * NCO + c] - a3;
    __syncthreads();
    if (t < 16) {
      for (int j = 63; j >= 0; --j) {
        float x = U[j][t];
        for (int j2 = j + 1; j2 < 64; ++j2) x = fmaf(-Ld[j][j2], xs[r0 + j2][t], x);
        x /= Ld[j][j];
        xs[r0 + j][t] = x;
        Odst[(size_t)(r0 + j) * NCO + t] = x;
      }
    }
    __syncthreads();
  }
}

// ---------------------------------------------------------------- epilogue
__global__ __launch_bounds__(256) void k_logdet(const float* __restrict__ P,
                                                float* __restrict__ accum) {
  int s = blockIdx.x;
  float part = 0.f;
  for (int i = threadIdx.x; i < NFF; i += 256)
    part += logf(P[(size_t)s * NFF * NFF + (size_t)i * NFF + i]);
  __shared__ float r[256];
  r[threadIdx.x] = part;
  __syncthreads();
  for (int off = 128; off > 0; off >>= 1) {
    if (threadIdx.x < off) r[threadIdx.x] += r[threadIdx.x + off];
    __syncthreads();
  }
  if (threadIdx.x == 0) {
    accum[s * 4 + 0] = 0.f;
    accum[s * 4 + 1] = 0.f;
    accum[s * 4 + 2] = 2.f * r[0];
  }
}

__global__ __launch_bounds__(256) void k_sample(const float* __restrict__ mu,
                                                const float* __restrict__ dW,
                                                const float* __restrict__ Z,
                                                float* __restrict__ sout,
                                                float* __restrict__ accum) {
  int s = blockIdx.y;
  int base = blockIdx.x * 2048;
  size_t so = (size_t)s * NFF * NCO;
  float s2 = 0.f, z2 = 0.f;
  for (int e = base + threadIdx.x; e < base + 2048; e += 256) {
    float v = mu[so + e] + dW[so + e];
    float z = Z[so + e];
    int f = e >> 7, cc = e & 127;
    sout[(size_t)s * NCO * NFF + (size_t)cc * NFF + f] = v;
    s2 = fmaf(v, v, s2);
    z2 = fmaf(z, z, z2);
  }
  __shared__ float r1[256], r2[256];
  r1[threadIdx.x] = s2;
  r2[threadIdx.x] = z2;
  __syncthreads();
  for (int off = 128; off > 0; off >>= 1) {
    if (threadIdx.x < off) {
      r1[threadIdx.x] += r1[threadIdx.x + off];
      r2[threadIdx.x] += r2[threadIdx.x + off];
    }
    __syncthreads();
  }
  if (threadIdx.x == 0) {
    atomicAdd(&accum[s * 4 + 0], r1[0]);
    atomicAdd(&accum[s * 4 + 1], r2[0]);
  }
}

__global__ void k_final(const float* __restrict__ accum, float* __restrict__ outLogpq) {
  int s = threadIdx.x;
  if (s < NS) {
    float s2 = accum[s * 4 + 0];
    float z2 = accum[s * 4 + 1];
    float ld = accum[s * 4 + 2];
    float logP = -0.5f * LAMV * s2 + 0.5f * (float)(NCO * NFF) * logf(LAMV);
    float logQ = -0.5f * z2 + 0.5f * (float)NCO * ld;
    outLogpq[s] = logP - logQ;
  }
}

// ---------------------------------------------------------------- launch
extern "C" void kernel_launch(void* const* d_in, const int* in_sizes, int n_in,
                              void* d_out, int out_size, void* d_ws, size_t ws_size,
                              hipStream_t stream) {
  const float* X = (const float*)d_in[0];
  const float* u = (const float*)d_in[1];
  const float* lp = (const float*)d_in[2];
  const float* Z = (const float*)d_in[3];
  float* out = (float*)d_out;

  const size_t XU2 = 18874368;   // 1152*8192*2 (bf16)
  const size_t BM2 = 2097152;    // 128*8192*2
  const size_t FF4 = 5308416;    // 1152*1152*4
  const size_t FC4 = 589824;     // 1152*128*4
  const size_t FC = 147456;      // elems
  const size_t FF = 1327104;     // elems
  const size_t XSTR = 1048576;   // X elems per s

  char* ws = (char*)d_ws;
  // region0: Xu(bf16)+Bm(bf16) early, later reused as LT (fp32)
  unsigned short* Xu = (unsigned short*)(ws);
  unsigned short* Bm = (unsigned short*)(ws + XU2);
  float* LTm = (float*)(ws);
  size_t off = 8 * FF4;                       // region0 = 42.5 MB (>= XU2+BM2)
  float* prec = (float*)(ws + off);  off += 8 * FF4;
  float* XLY = (float*)(ws + off);   off += 8 * FC4;
  float* t1 = (float*)(ws + off);    off += 8 * FC4;
  float* muB = (float*)(ws + off);   off += 8 * FC4;
  float* dWB = (float*)(ws + off);   off += 8 * FC4;
  float* accum = (float*)(ws + off);

  k_build_B<<<4096, 256, 0, stream>>>(u, lp, Bm);
  hipMemsetAsync(prec, 0, 8 * FF4, stream);
  hipMemsetAsync(XLY, 0, 8 * FC4, stream);
  k_diag_init<<<dim3(5, 8), 256, 0, stream>>>(prec);

  for (int sg = 0; sg < NS; ++sg) {
    k_build_Xu<<<36864, 256, 0, stream>>>(X + (size_t)sg * XSTR, lp, Xu);
    k_mfma<<<dim3(54, 8), 256, 0, stream>>>(Xu, Bm, prec + (size_t)sg * FF,
                                            XLY + (size_t)sg * FC);
  }

  for (int p = 0; p < 9; ++p) {
    k_chol_diag<<<8, 256, 0, stream>>>(prec, p);
    if (p < 8) {
      int T = 8 - p;
      k_chol_panel<<<dim3(T, 8), 128, 0, stream>>>(prec, p);
      k_chol_trail<<<dim3(T * (T + 1) / 2, 8), 256, 0, stream>>>(prec, p);
    }
  }

  k_transpose<<<dim3(36, 36, 8), 256, 0, stream>>>(prec, LTm);
  k_fwd_solve<<<dim3(8, 8), 256, 0, stream>>>(prec, XLY, t1);
  k_bwd_solve<<<dim3(16, 8), 256, 0, stream>>>(LTm, t1, muB, Z, dWB);

  k_logdet<<<8, 256, 0, stream>>>(prec, accum);
  k_sample<<<dim3(72, 8), 256, 0, stream>>>(muB, dWB, Z, out, accum);
  k_final<<<1, 64, 0, stream>>>(accum, out + (size_t)NS * FC);
}

// Round 4
// 5119.941 us; speedup vs baseline: 3.3150x; 1.6972x over previous
//
#include <hip/hip_runtime.h>
#include <hip/hip_bf16.h>
#include <math.h>

#define NS    8
#define NNI   32
#define NCI   128
#define NHH   16
#define NWW   16
#define NCO   128
#define NFF   1152
#define NLL   256
#define LAMV  1152.0f

typedef short s8v __attribute__((ext_vector_type(8)));
typedef float f4v __attribute__((ext_vector_type(4)));

#define AS1 __attribute__((address_space(1)))
#define AS3 __attribute__((address_space(3)))

// ---------------------------------------------------------------- build Xu (bf16) for one s
__global__ __launch_bounds__(256) void k_build_Xu(const float* __restrict__ X,
                                                  const float* __restrict__ lp,
                                                  unsigned short* __restrict__ Xu) {
  unsigned idx = blockIdx.x * 256u + threadIdx.x;   // < 1152*8192
  unsigned m = idx & 8191u;
  unsigned f = idx >> 13;
  unsigned n = m >> 8, l = m & 255u, h = l >> 4, w = l & 15u;
  unsigned c = f / 9u, a = f - 9u * c;
  unsigned ki = a / 3u, kj = a - 3u * ki;
  int hi = (int)(h + ki) - 1, wi = (int)(w + kj) - 1;
  float v = 0.f;
  if (hi >= 0 && hi < NHH && wi >= 0 && wi < NWW)
    v = X[(((size_t)n * NCI + c) << 8) + (unsigned)(hi * NWW + wi)];
  float sp = expf(0.5f * lp[n]);
  __hip_bfloat16 hv = __float2bfloat16(sp * v);
  Xu[idx] = *(unsigned short*)&hv;
}

__global__ __launch_bounds__(256) void k_build_B(const float* __restrict__ u,
                                                 const float* __restrict__ lp,
                                                 unsigned short* __restrict__ Bm) {
  unsigned idx = blockIdx.x * 256u + threadIdx.x;   // < 1,048,576
  unsigned m = idx & 8191u;
  unsigned c = idx >> 13;
  unsigned n = m >> 8, l = m & 255u;
  float sp = expf(0.5f * lp[n]);
  __hip_bfloat16 hv = __float2bfloat16(sp * u[((size_t)n * NCO + c) * NLL + l]);
  Bm[idx] = *(unsigned short*)&hv;
}

__global__ void k_diag_init(float* __restrict__ prec) {
  int s = blockIdx.y;
  int i = blockIdx.x * 256 + threadIdx.x;
  if (i < NFF) prec[(size_t)s * NFF * NFF + (size_t)i * NFF + i] = LAMV;
}

// ---------------------------------------------------------------- MFMA bf16 GEMM (one s per launch)
__global__ __launch_bounds__(256) void k_mfma(const unsigned short* __restrict__ Xu,
                                              const unsigned short* __restrict__ Bm,
                                              float* __restrict__ prec,
                                              float* __restrict__ XLY) {
  __shared__ unsigned short As[8192];
  __shared__ unsigned short Bs[8192];
  int bx = blockIdx.x;
  int row0, col0;
  const unsigned short* Ag;
  const unsigned short* Bg;
  bool isXLX;
  if (bx < 45) {
    int b = 0;
    while ((b + 1) * (b + 2) / 2 <= bx) b++;
    row0 = b * 128;
    col0 = (bx - b * (b + 1) / 2) * 128;
    Bg = Xu + (size_t)col0 * 8192;
    isXLX = true;
  } else {
    row0 = (bx - 45) * 128;
    col0 = 0;
    Bg = Bm;
    isXLX = false;
  }
  Ag = Xu + (size_t)row0 * 8192;

  int t = threadIdx.x;
  int lane = t & 63, w = t >> 6;
  int wm = w & 1, wn = w >> 1;
  int n16 = lane & 15, q = lane >> 4;
  int srow = lane >> 3, sch = lane & 7;

  f4v acc[4][4];
#pragma unroll
  for (int i = 0; i < 4; ++i)
#pragma unroll
    for (int j = 0; j < 4; ++j) acc[i][j] = (f4v)0.f;

  int kBase = blockIdx.y * 1024;
  for (int k0 = kBase; k0 < kBase + 1024; k0 += 64) {
    __syncthreads();
#pragma unroll
    for (int it = 0; it < 4; ++it) {
      int rA = (w * 4 + it) * 8 + srow;
      int cA = (sch - rA) & 7;
      const unsigned short* gpa = Ag + (size_t)rA * 8192 + k0 + cA * 8;
      const unsigned short* gpb = Bg + (size_t)rA * 8192 + k0 + cA * 8;
      __builtin_amdgcn_global_load_lds((AS1 const void*)gpa,
                                       (AS3 void*)&As[(w * 4 + it) * 512], 16, 0, 0);
      __builtin_amdgcn_global_load_lds((AS1 const void*)gpb,
                                       (AS3 void*)&Bs[(w * 4 + it) * 512], 16, 0, 0);
    }
    __syncthreads();
#pragma unroll
    for (int kk = 0; kk < 2; ++kk) {
      s8v af[4], bf[4];
#pragma unroll
      for (int im = 0; im < 4; ++im) {
        int r = wm * 64 + im * 16 + n16;
        int slot = ((kk * 4 + q) + r) & 7;
        af[im] = *(const s8v*)&As[r * 64 + slot * 8];
      }
#pragma unroll
      for (int in = 0; in < 4; ++in) {
        int r = wn * 64 + in * 16 + n16;
        int slot = ((kk * 4 + q) + r) & 7;
        bf[in] = *(const s8v*)&Bs[r * 64 + slot * 8];
      }
#pragma unroll
      for (int im = 0; im < 4; ++im)
#pragma unroll
        for (int in = 0; in < 4; ++in)
          acc[im][in] = __builtin_amdgcn_mfma_f32_16x16x32_bf16(af[im], bf[in], acc[im][in], 0, 0, 0);
    }
  }

  if (isXLX) {
#pragma unroll
    for (int im = 0; im < 4; ++im)
#pragma unroll
      for (int in = 0; in < 4; ++in) {
        int gr = row0 + wm * 64 + im * 16 + q * 4;
        int gc = col0 + wn * 64 + in * 16 + n16;
#pragma unroll
        for (int tt = 0; tt < 4; ++tt)
          atomicAdd(&prec[(size_t)(gr + tt) * NFF + gc], acc[im][in][tt]);
      }
  } else {
#pragma unroll
    for (int im = 0; im < 4; ++im)
#pragma unroll
      for (int in = 0; in < 4; ++in) {
        int gr = row0 + wm * 64 + im * 16 + q * 4;
        int gc = wn * 64 + in * 16 + n16;
#pragma unroll
        for (int tt = 0; tt < 4; ++tt)
          atomicAdd(&XLY[(size_t)(gr + tt) * NCO + gc], acc[im][in][tt]);
      }
  }
}

// ---------------------------------------------------------------- Cholesky NB=128
__global__ __launch_bounds__(256) void k_chol_diag(float* __restrict__ P, int p) {
  int s = blockIdx.x;
  float* Ps = P + (size_t)s * NFF * NFF;
  __shared__ float D[128][129];
  int t = threadIdx.x;
  int pc = p * 128;
  for (int e = t; e < 16384; e += 256)
    D[e >> 7][e & 127] = Ps[(size_t)(pc + (e >> 7)) * NFF + pc + (e & 127)];
  int i2 = t & 127, kh = t >> 7;
  for (int j = 0; j < 128; ++j) {
    __syncthreads();
    float dv = D[j][j];
    float dj = sqrtf(dv);
    float inv = 1.0f / dj;
    __syncthreads();
    if (t == 0) D[j][j] = dj;
    for (int i = j + 1 + t; i < 128; i += 256) D[i][j] *= inv;
    __syncthreads();
    int i = j + 1 + i2;
    if (i < 128) {
      float lij = D[i][j];
      for (int k = j + 1 + kh; k <= i; k += 2) D[i][k] = fmaf(-lij, D[k][j], D[i][k]);
    }
  }
  __syncthreads();
  for (int e = t; e < 16384; e += 256) {
    int r = e >> 7, cc = e & 127;
    if (cc <= r) Ps[(size_t)(pc + r) * NFF + pc + cc] = D[r][cc];
  }
}

__global__ __launch_bounds__(128) void k_chol_panel(float* __restrict__ P, int p) {
  int s = blockIdx.y;
  float* Ps = P + (size_t)s * NFF * NFF;
  __shared__ float L11[128][129];
  __shared__ float A2[128][129];
  int t = threadIdx.x;
  int pc = p * 128, r0 = (p + 1 + (int)blockIdx.x) * 128;
  for (int e = t; e < 16384; e += 128) {
    L11[e >> 7][e & 127] = Ps[(size_t)(pc + (e >> 7)) * NFF + pc + (e & 127)];
    A2[e >> 7][e & 127] = Ps[(size_t)(r0 + (e >> 7)) * NFF + pc + (e & 127)];
  }
  __syncthreads();
  for (int j = 0; j < 128; ++j) {
    float v = A2[t][j] / L11[j][j];
    A2[t][j] = v;
    for (int k = j + 1; k < 128; ++k) A2[t][k] = fmaf(-v, L11[k][j], A2[t][k]);
  }
  __syncthreads();
  for (int e = t; e < 16384; e += 128)
    Ps[(size_t)(r0 + (e >> 7)) * NFF + pc + (e & 127)] = A2[e >> 7][e & 127];
}

__global__ __launch_bounds__(256) void k_chol_trail(float* __restrict__ P, int p) {
  int s = blockIdx.y;
  float* Ps = P + (size_t)s * NFF * NFF;
  int idx = blockIdx.x;
  int b = 0;
  while ((b + 1) * (b + 2) / 2 <= idx) b++;
  int bi = p + 1 + b, bj = p + 1 + (idx - b * (b + 1) / 2);
  int pc = p * 128;
  const float* Ag = Ps + (size_t)(bi * 128) * NFF + pc;
  const float* Bg = Ps + (size_t)(bj * 128) * NFF + pc;
  __shared__ float As_[16][132];
  __shared__ float Bs_[16][132];
  int tid = threadIdx.x;
  int tx = tid & 15, ty = tid >> 4;
  int lr = tid >> 2, lc = tid & 3;
  float acc[8][8];
#pragma unroll
  for (int i = 0; i < 8; ++i)
#pragma unroll
    for (int j = 0; j < 8; ++j) acc[i][j] = 0.f;
  for (int k0 = 0; k0 < 128; k0 += 16) {
    float4 a0 = *(const float4*)(Ag + (size_t)lr * NFF + k0 + lc * 4);
    float4 a1 = *(const float4*)(Ag + (size_t)(lr + 64) * NFF + k0 + lc * 4);
    float4 b0 = *(const float4*)(Bg + (size_t)lr * NFF + k0 + lc * 4);
    float4 b1 = *(const float4*)(Bg + (size_t)(lr + 64) * NFF + k0 + lc * 4);
    __syncthreads();
    As_[lc * 4 + 0][lr] = a0.x; As_[lc * 4 + 1][lr] = a0.y;
    As_[lc * 4 + 2][lr] = a0.z; As_[lc * 4 + 3][lr] = a0.w;
    As_[lc * 4 + 0][lr + 64] = a1.x; As_[lc * 4 + 1][lr + 64] = a1.y;
    As_[lc * 4 + 2][lr + 64] = a1.z; As_[lc * 4 + 3][lr + 64] = a1.w;
    Bs_[lc * 4 + 0][lr] = b0.x; Bs_[lc * 4 + 1][lr] = b0.y;
    Bs_[lc * 4 + 2][lr] = b0.z; Bs_[lc * 4 + 3][lr] = b0.w;
    Bs_[lc * 4 + 0][lr + 64] = b1.x; Bs_[lc * 4 + 1][lr + 64] = b1.y;
    Bs_[lc * 4 + 2][lr + 64] = b1.z; Bs_[lc * 4 + 3][lr + 64] = b1.w;
    __syncthreads();
#pragma unroll
    for (int k = 0; k < 16; ++k) {
      float av[8], bv[8];
      *(float4*)&av[0] = *(const float4*)&As_[k][ty * 8];
      *(float4*)&av[4] = *(const float4*)&As_[k][ty * 8 + 4];
      *(float4*)&bv[0] = *(const float4*)&Bs_[k][tx * 8];
      *(float4*)&bv[4] = *(const float4*)&Bs_[k][tx * 8 + 4];
#pragma unroll
      for (int i = 0; i < 8; ++i)
#pragma unroll
        for (int j = 0; j < 8; ++j) acc[i][j] = fmaf(av[i], bv[j], acc[i][j]);
    }
  }
#pragma unroll
  for (int i = 0; i < 8; ++i) {
    float* crow = Ps + (size_t)(bi * 128 + ty * 8 + i) * NFF + bj * 128 + tx * 8;
    float4 c0 = *(float4*)crow;
    float4 c1 = *(float4*)(crow + 4);
    c0.x -= acc[i][0]; c0.y -= acc[i][1]; c0.z -= acc[i][2]; c0.w -= acc[i][3];
    c1.x -= acc[i][4]; c1.y -= acc[i][5]; c1.z -= acc[i][6]; c1.w -= acc[i][7];
    *(float4*)crow = c0;
    *(float4*)(crow + 4) = c1;
  }
}

// ---------------------------------------------------------------- explicit inverse W = L^{-1}
// invert all 18 diagonal 64-blocks; thread t solves column t by fwd substitution
__global__ __launch_bounds__(64) void k_invdiag(const float* __restrict__ P,
                                                float* __restrict__ W) {
  int ib = blockIdx.x, s = blockIdx.y;
  const float* Ps = P + (size_t)s * NFF * NFF + (size_t)(ib * 64) * NFF + ib * 64;
  float* Ws = W + (size_t)s * NFF * NFF + (size_t)(ib * 64) * NFF + ib * 64;
  __shared__ float Lt[64][65];
  __shared__ float xc[64][66];
  int t = threadIdx.x;
  for (int e = t; e < 4096; e += 64)
    Lt[e >> 6][e & 63] = Ps[(size_t)(e >> 6) * NFF + (e & 63)];
  __syncthreads();
  for (int j = 0; j < 64; ++j) {
    float v = (j == t) ? 1.f : 0.f;
    for (int k = t; k < j; ++k) v = fmaf(-Lt[j][k], xc[k][t], v);
    xc[j][t] = v / Lt[j][j];
  }
  for (int j = 0; j < 64; ++j)
    Ws[(size_t)j * NFF + t] = (j >= t) ? xc[j][t] : 0.f;
}

// off-diagonal blocks by diagonals: W[i][j] = -W[i][i] * sum_{k=j..i-1} L[i][k] W[k][j], i=j+d
__global__ __launch_bounds__(256) void k_invoff(const float* __restrict__ P,
                                                float* __restrict__ W, int d) {
  int j = blockIdx.x, s = blockIdx.y;
  int i = j + d;
  const float* Ps = P + (size_t)s * NFF * NFF;
  float* Ws = W + (size_t)s * NFF * NFF;
  __shared__ float At[64][65];
  __shared__ float Bt[64][65];
  __shared__ float Tt[64][65];
  int t = threadIdx.x, tx = t & 15, ty = t >> 4;
  int r = t >> 2;
  float acc[4][4];
#pragma unroll
  for (int a = 0; a < 4; ++a)
#pragma unroll
    for (int b = 0; b < 4; ++b) acc[a][b] = 0.f;

  for (int kb = j; kb < i; ++kb) {
    __syncthreads();
    const float* Lp = Ps + (size_t)(i * 64) * NFF + kb * 64;
    const float* Wp = Ws + (size_t)(kb * 64) * NFF + j * 64;
#pragma unroll
    for (int it = 0; it < 4; ++it) {
      int cc = (t & 3) * 4 + it * 16;
      float4 a = *(const float4*)(Lp + (size_t)r * NFF + cc);
      float4 b = *(const float4*)(Wp + (size_t)r * NFF + cc);
      At[cc + 0][r] = a.x; At[cc + 1][r] = a.y; At[cc + 2][r] = a.z; At[cc + 3][r] = a.w;
      Bt[r][cc + 0] = b.x; Bt[r][cc + 1] = b.y; Bt[r][cc + 2] = b.z; Bt[r][cc + 3] = b.w;
    }
    __syncthreads();
#pragma unroll 8
    for (int kk = 0; kk < 64; ++kk) {
      float av[4], bv[4];
#pragma unroll
      for (int a = 0; a < 4; ++a) av[a] = At[kk][ty * 4 + a];
#pragma unroll
      for (int b = 0; b < 4; ++b) bv[b] = Bt[kk][tx * 4 + b];
#pragma unroll
      for (int a = 0; a < 4; ++a)
#pragma unroll
        for (int b = 0; b < 4; ++b) acc[a][b] = fmaf(av[a], bv[b], acc[a][b]);
    }
  }
  __syncthreads();
#pragma unroll
  for (int a = 0; a < 4; ++a)
#pragma unroll
    for (int b = 0; b < 4; ++b) Tt[ty * 4 + a][tx * 4 + b] = acc[a][b];
  {
    const float* Dp = Ws + (size_t)(i * 64) * NFF + i * 64;
#pragma unroll
    for (int it = 0; it < 4; ++it) {
      int cc = (t & 3) * 4 + it * 16;
      float4 a = *(const float4*)(Dp + (size_t)r * NFF + cc);
      At[cc + 0][r] = a.x; At[cc + 1][r] = a.y; At[cc + 2][r] = a.z; At[cc + 3][r] = a.w;
    }
  }
  __syncthreads();
  float acc2[4][4];
#pragma unroll
  for (int a = 0; a < 4; ++a)
#pragma unroll
    for (int b = 0; b < 4; ++b) acc2[a][b] = 0.f;
#pragma unroll 8
  for (int kk = 0; kk < 64; ++kk) {
    float av[4], bv[4];
#pragma unroll
    for (int a = 0; a < 4; ++a) av[a] = At[kk][ty * 4 + a];
#pragma unroll
    for (int b = 0; b < 4; ++b) bv[b] = Tt[kk][tx * 4 + b];
#pragma unroll
    for (int a = 0; a < 4; ++a)
#pragma unroll
      for (int b = 0; b < 4; ++b) acc2[a][b] = fmaf(av[a], bv[b], acc2[a][b]);
  }
  float* Wo = Ws + (size_t)(i * 64) * NFF + j * 64;
#pragma unroll
  for (int a = 0; a < 4; ++a)
#pragma unroll
    for (int b = 0; b < 4; ++b)
      Wo[(size_t)(ty * 4 + a) * NFF + tx * 4 + b] = -acc2[a][b];
}

// ---------------------------------------------------------------- apply: t1R = W*XLY + Z (+sumZ^2)
__global__ __launch_bounds__(256) void k_app1(const float* __restrict__ W,
                                              const float* __restrict__ XLY,
                                              const float* __restrict__ Z,
                                              float* __restrict__ t1R,
                                              float* __restrict__ accum) {
  int rb = blockIdx.x, s = blockIdx.y;
  int r0 = rb * 64;
  const float* Ws = W + (size_t)s * NFF * NFF;
  const float* Ys = XLY + (size_t)s * NFF * NCO;
  const float* Zs = Z + (size_t)s * NFF * NCO;
  float* Os = t1R + (size_t)s * NFF * NCO;
  __shared__ float As_[16][68];
  __shared__ float Bs_[16][132];
  __shared__ float red[256];
  int t = threadIdx.x, tx = t & 15, ty = t >> 4;
  float acc[4][8];
#pragma unroll
  for (int a = 0; a < 4; ++a)
#pragma unroll
    for (int b = 0; b < 8; ++b) acc[a][b] = 0.f;
  int kmax = r0 + 64;
  for (int k0 = 0; k0 < kmax; k0 += 16) {
    float4 a = *(const float4*)(Ws + (size_t)(r0 + (t >> 2)) * NFF + k0 + (t & 3) * 4);
    float4 b0 = *(const float4*)(Ys + (size_t)(k0 + (t >> 4)) * NCO + (t & 15) * 8);
    float4 b1 = *(const float4*)(Ys + (size_t)(k0 + (t >> 4)) * NCO + (t & 15) * 8 + 4);
    __syncthreads();
    As_[(t & 3) * 4 + 0][t >> 2] = a.x; As_[(t & 3) * 4 + 1][t >> 2] = a.y;
    As_[(t & 3) * 4 + 2][t >> 2] = a.z; As_[(t & 3) * 4 + 3][t >> 2] = a.w;
    *(float4*)&Bs_[t >> 4][(t & 15) * 8] = b0;
    *(float4*)&Bs_[t >> 4][(t & 15) * 8 + 4] = b1;
    __syncthreads();
#pragma unroll
    for (int kk = 0; kk < 16; ++kk) {
      float av[4], bv[8];
#pragma unroll
      for (int a2 = 0; a2 < 4; ++a2) av[a2] = As_[kk][ty * 4 + a2];
      *(float4*)&bv[0] = *(const float4*)&Bs_[kk][tx * 8];
      *(float4*)&bv[4] = *(const float4*)&Bs_[kk][tx * 8 + 4];
#pragma unroll
      for (int a2 = 0; a2 < 4; ++a2)
#pragma unroll
        for (int b2 = 0; b2 < 8; ++b2) acc[a2][b2] = fmaf(av[a2], bv[b2], acc[a2][b2]);
    }
  }
  float z2 = 0.f;
#pragma unroll
  for (int a2 = 0; a2 < 4; ++a2) {
    int row = r0 + ty * 4 + a2;
    const float* zp = Zs + (size_t)row * NCO + tx * 8;
    float* op = Os + (size_t)row * NCO + tx * 8;
    float4 z0 = *(const float4*)zp;
    float4 z1 = *(const float4*)(zp + 4);
    float4 v0, v1;
    v0.x = acc[a2][0] + z0.x; v0.y = acc[a2][1] + z0.y;
    v0.z = acc[a2][2] + z0.z; v0.w = acc[a2][3] + z0.w;
    v1.x = acc[a2][4] + z1.x; v1.y = acc[a2][5] + z1.y;
    v1.z = acc[a2][6] + z1.z; v1.w = acc[a2][7] + z1.w;
    z2 += z0.x * z0.x + z0.y * z0.y + z0.z * z0.z + z0.w * z0.w;
    z2 += z1.x * z1.x + z1.y * z1.y + z1.z * z1.z + z1.w * z1.w;
    *(float4*)op = v0;
    *(float4*)(op + 4) = v1;
  }
  __syncthreads();
  red[t] = z2;
  __syncthreads();
  for (int o = 128; o > 0; o >>= 1) {
    if (t < o) red[t] += red[t + o];
    __syncthreads();
  }
  if (t == 0) atomicAdd(&accum[s * 4 + 1], red[0]);
}

// ---------------------------------------------------------------- apply: sample = W^T * t1R (transposed store, +sum S^2)
__global__ __launch_bounds__(256) void k_app2(const float* __restrict__ W,
                                              const float* __restrict__ t1R,
                                              float* __restrict__ sout,
                                              float* __restrict__ accum) {
  int rb = blockIdx.x, s = blockIdx.y;
  int r0 = rb * 64;
  const float* Ws = W + (size_t)s * NFF * NFF;
  const float* Rs = t1R + (size_t)s * NFF * NCO;
  float* Op = sout + (size_t)s * NCO * NFF;
  __shared__ float As_[16][68];
  __shared__ float Bs_[16][132];
  __shared__ float red[256];
  int t = threadIdx.x, tx = t & 15, ty = t >> 4;
  float acc[4][8];
#pragma unroll
  for (int a = 0; a < 4; ++a)
#pragma unroll
    for (int b = 0; b < 8; ++b) acc[a][b] = 0.f;
  for (int k0 = r0; k0 < NFF; k0 += 16) {
    float4 a = *(const float4*)(Ws + (size_t)(k0 + (t >> 4)) * NFF + r0 + (t & 15) * 4);
    float4 b0 = *(const float4*)(Rs + (size_t)(k0 + (t >> 4)) * NCO + (t & 15) * 8);
    float4 b1 = *(const float4*)(Rs + (size_t)(k0 + (t >> 4)) * NCO + (t & 15) * 8 + 4);
    __syncthreads();
    *(float4*)&As_[t >> 4][(t & 15) * 4] = a;
    *(float4*)&Bs_[t >> 4][(t & 15) * 8] = b0;
    *(float4*)&Bs_[t >> 4][(t & 15) * 8 + 4] = b1;
    __syncthreads();
#pragma unroll
    for (int kk = 0; kk < 16; ++kk) {
      float av[4], bv[8];
#pragma unroll
      for (int a2 = 0; a2 < 4; ++a2) av[a2] = As_[kk][ty * 4 + a2];
      *(float4*)&bv[0] = *(const float4*)&Bs_[kk][tx * 8];
      *(float4*)&bv[4] = *(const float4*)&Bs_[kk][tx * 8 + 4];
#pragma unroll
      for (int a2 = 0; a2 < 4; ++a2)
#pragma unroll
        for (int b2 = 0; b2 < 8; ++b2) acc[a2][b2] = fmaf(av[a2], bv[b2], acc[a2][b2]);
    }
  }
  float s2 = 0.f;
#pragma unroll
  for (int b2 = 0; b2 < 8; ++b2) {
    int col = tx * 8 + b2;
    float4 v;
    v.x = acc[0][b2]; v.y = acc[1][b2]; v.z = acc[2][b2]; v.w = acc[3][b2];
    s2 += v.x * v.x + v.y * v.y + v.z * v.z + v.w * v.w;
    *(float4*)(Op + (size_t)col * NFF + r0 + ty * 4) = v;
  }
  __syncthreads();
  red[t] = s2;
  __syncthreads();
  for (int o = 128; o > 0; o >>= 1) {
    if (t < o) red[t] += red[t + o];
    __syncthreads();
  }
  if (t == 0) atomicAdd(&accum[s * 4 + 0], red[0]);
}

// ---------------------------------------------------------------- epilogue
__global__ __launch_bounds__(256) void k_logdet(const float* __restrict__ P,
                                                float* __restrict__ accum) {
  int s = blockIdx.x;
  float part = 0.f;
  for (int i = threadIdx.x; i < NFF; i += 256)
    part += logf(P[(size_t)s * NFF * NFF + (size_t)i * NFF + i]);
  __shared__ float r[256];
  r[threadIdx.x] = part;
  __syncthreads();
  for (int off = 128; off > 0; off >>= 1) {
    if (threadIdx.x < off) r[threadIdx.x] += r[threadIdx.x + off];
    __syncthreads();
  }
  if (threadIdx.x == 0) {
    accum[s * 4 + 0] = 0.f;
    accum[s * 4 + 1] = 0.f;
    accum[s * 4 + 2] = 2.f * r[0];
  }
}

__global__ void k_final(const float* __restrict__ accum, float* __restrict__ outLogpq) {
  int s = threadIdx.x;
  if (s < NS) {
    float s2 = accum[s * 4 + 0];
    float z2 = accum[s * 4 + 1];
    float ld = accum[s * 4 + 2];
    float logP = -0.5f * LAMV * s2 + 0.5f * (float)(NCO * NFF) * logf(LAMV);
    float logQ = -0.5f * z2 + 0.5f * (float)NCO * ld;
    outLogpq[s] = logP - logQ;
  }
}

// ---------------------------------------------------------------- launch
extern "C" void kernel_launch(void* const* d_in, const int* in_sizes, int n_in,
                              void* d_out, int out_size, void* d_ws, size_t ws_size,
                              hipStream_t stream) {
  const float* X = (const float*)d_in[0];
  const float* u = (const float*)d_in[1];
  const float* lp = (const float*)d_in[2];
  const float* Z = (const float*)d_in[3];
  float* out = (float*)d_out;

  const size_t XU2 = 18874368;   // 1152*8192*2 (bf16)
  const size_t FF4 = 5308416;    // 1152*1152*4
  const size_t FC4 = 589824;     // 1152*128*4
  const size_t FC = 147456;      // elems
  const size_t FF = 1327104;     // elems
  const size_t XSTR = 1048576;   // X elems per s

  char* ws = (char*)d_ws;
  // region0 (42.5 MB): Xu(bf16)+Bm(bf16) early, reused as W (fp32) after GEMMs
  unsigned short* Xu = (unsigned short*)(ws);
  unsigned short* Bm = (unsigned short*)(ws + XU2);
  float* W = (float*)(ws);
  size_t off = 8 * FF4;
  float* prec = (float*)(ws + off); off += 8 * FF4;
  float* XLY = (float*)(ws + off);  off += 8 * FC4;
  float* t1R = (float*)(ws + off);  off += 8 * FC4;
  float* accum = (float*)(ws + off);

  k_build_B<<<4096, 256, 0, stream>>>(u, lp, Bm);
  hipMemsetAsync(prec, 0, 8 * FF4, stream);
  hipMemsetAsync(XLY, 0, 8 * FC4, stream);
  k_diag_init<<<dim3(5, 8), 256, 0, stream>>>(prec);

  for (int sg = 0; sg < NS; ++sg) {
    k_build_Xu<<<36864, 256, 0, stream>>>(X + (size_t)sg * XSTR, lp, Xu);
    k_mfma<<<dim3(54, 8), 256, 0, stream>>>(Xu, Bm, prec + (size_t)sg * FF,
                                            XLY + (size_t)sg * FC);
  }

  for (int p = 0; p < 9; ++p) {
    k_chol_diag<<<8, 256, 0, stream>>>(prec, p);
    if (p < 8) {
      int T = 8 - p;
      k_chol_panel<<<dim3(T, 8), 128, 0, stream>>>(prec, p);
      k_chol_trail<<<dim3(T * (T + 1) / 2, 8), 256, 0, stream>>>(prec, p);
    }
  }

  k_logdet<<<8, 256, 0, stream>>>(prec, accum);

  // explicit inverse W = L^{-1}
  hipMemsetAsync(W, 0, 8 * FF4, stream);
  k_invdiag<<<dim3(18, 8), 64, 0, stream>>>(prec, W);
  for (int d = 1; d < 18; ++d)
    k_invoff<<<dim3(18 - d, 8), 256, 0, stream>>>(prec, W, d);

  // sample = W^T (W XLY + Z); fused reductions
  k_app1<<<dim3(18, 8), 256, 0, stream>>>(W, XLY, Z, t1R, accum);
  k_app2<<<dim3(18, 8), 256, 0, stream>>>(W, t1R, out, accum);
  k_final<<<1, 64, 0, stream>>>(accum, out + (size_t)NS * FC);
}

// Round 5
// 3763.583 us; speedup vs baseline: 4.5097x; 1.3604x over previous
//
#include <hip/hip_runtime.h>
#include <hip/hip_bf16.h>
#include <math.h>

#define NS    8
#define NNI   32
#define NCI   128
#define NHH   16
#define NWW   16
#define NCO   128
#define NFF   1152
#define NLL   256
#define LAMV  1152.0f

typedef short s8v __attribute__((ext_vector_type(8)));
typedef float f4v __attribute__((ext_vector_type(4)));

#define AS1 __attribute__((address_space(1)))
#define AS3 __attribute__((address_space(3)))

// ---------------------------------------------------------------- build Xu (bf16), two s per launch (blockIdx.y)
__global__ __launch_bounds__(256) void k_build_Xu(const float* __restrict__ X,
                                                  const float* __restrict__ lp,
                                                  unsigned short* __restrict__ Xu) {
  unsigned z = blockIdx.y;
  unsigned idx = blockIdx.x * 256u + threadIdx.x;   // < 1152*8192
  unsigned m = idx & 8191u;
  unsigned f = idx >> 13;
  unsigned n = m >> 8, l = m & 255u, h = l >> 4, w = l & 15u;
  unsigned c = f / 9u, a = f - 9u * c;
  unsigned ki = a / 3u, kj = a - 3u * ki;
  int hi = (int)(h + ki) - 1, wi = (int)(w + kj) - 1;
  float v = 0.f;
  if (hi >= 0 && hi < NHH && wi >= 0 && wi < NWW)
    v = X[(size_t)z * 1048576 + (((size_t)n * NCI + c) << 8) + (unsigned)(hi * NWW + wi)];
  float sp = expf(0.5f * lp[n]);
  __hip_bfloat16 hv = __float2bfloat16(sp * v);
  Xu[(size_t)z * (NFF * 8192) + idx] = *(unsigned short*)&hv;
}

__global__ __launch_bounds__(256) void k_build_B(const float* __restrict__ u,
                                                 const float* __restrict__ lp,
                                                 unsigned short* __restrict__ Bm) {
  unsigned idx = blockIdx.x * 256u + threadIdx.x;   // < 1,048,576
  unsigned m = idx & 8191u;
  unsigned c = idx >> 13;
  unsigned n = m >> 8, l = m & 255u;
  float sp = expf(0.5f * lp[n]);
  __hip_bfloat16 hv = __float2bfloat16(sp * u[((size_t)n * NCO + c) * NLL + l]);
  Bm[idx] = *(unsigned short*)&hv;
}

__global__ void k_diag_init(float* __restrict__ prec) {
  int s = blockIdx.y;
  int i = blockIdx.x * 256 + threadIdx.x;
  if (i < NFF) prec[(size_t)s * NFF * NFF + (size_t)i * NFF + i] = LAMV;
}

// ---------------------------------------------------------------- MFMA bf16 GEMM, two s per launch (blockIdx.z)
__global__ __launch_bounds__(256) void k_mfma(const unsigned short* __restrict__ XuBase,
                                              const unsigned short* __restrict__ Bm,
                                              float* __restrict__ prec,
                                              float* __restrict__ XLY) {
  __shared__ unsigned short As[8192];
  __shared__ unsigned short Bs[8192];
  int z = blockIdx.z;
  const unsigned short* Xu = XuBase + (size_t)z * (NFF * 8192);
  prec += (size_t)z * NFF * NFF;
  XLY += (size_t)z * NFF * NCO;
  int bx = blockIdx.x;
  int row0, col0;
  const unsigned short* Ag;
  const unsigned short* Bg;
  bool isXLX;
  if (bx < 45) {
    int b = 0;
    while ((b + 1) * (b + 2) / 2 <= bx) b++;
    row0 = b * 128;
    col0 = (bx - b * (b + 1) / 2) * 128;
    Bg = Xu + (size_t)col0 * 8192;
    isXLX = true;
  } else {
    row0 = (bx - 45) * 128;
    col0 = 0;
    Bg = Bm;
    isXLX = false;
  }
  Ag = Xu + (size_t)row0 * 8192;

  int t = threadIdx.x;
  int lane = t & 63, w = t >> 6;
  int wm = w & 1, wn = w >> 1;
  int n16 = lane & 15, q = lane >> 4;
  int srow = lane >> 3, sch = lane & 7;

  f4v acc[4][4];
#pragma unroll
  for (int i = 0; i < 4; ++i)
#pragma unroll
    for (int j = 0; j < 4; ++j) acc[i][j] = (f4v)0.f;

  int kBase = blockIdx.y * 1024;
  for (int k0 = kBase; k0 < kBase + 1024; k0 += 64) {
    __syncthreads();
#pragma unroll
    for (int it = 0; it < 4; ++it) {
      int rA = (w * 4 + it) * 8 + srow;
      int cA = (sch - rA) & 7;
      const unsigned short* gpa = Ag + (size_t)rA * 8192 + k0 + cA * 8;
      const unsigned short* gpb = Bg + (size_t)rA * 8192 + k0 + cA * 8;
      __builtin_amdgcn_global_load_lds((AS1 const void*)gpa,
                                       (AS3 void*)&As[(w * 4 + it) * 512], 16, 0, 0);
      __builtin_amdgcn_global_load_lds((AS1 const void*)gpb,
                                       (AS3 void*)&Bs[(w * 4 + it) * 512], 16, 0, 0);
    }
    __syncthreads();
#pragma unroll
    for (int kk = 0; kk < 2; ++kk) {
      s8v af[4], bf[4];
#pragma unroll
      for (int im = 0; im < 4; ++im) {
        int r = wm * 64 + im * 16 + n16;
        int slot = ((kk * 4 + q) + r) & 7;
        af[im] = *(const s8v*)&As[r * 64 + slot * 8];
      }
#pragma unroll
      for (int in = 0; in < 4; ++in) {
        int r = wn * 64 + in * 16 + n16;
        int slot = ((kk * 4 + q) + r) & 7;
        bf[in] = *(const s8v*)&Bs[r * 64 + slot * 8];
      }
#pragma unroll
      for (int im = 0; im < 4; ++im)
#pragma unroll
        for (int in = 0; in < 4; ++in)
          acc[im][in] = __builtin_amdgcn_mfma_f32_16x16x32_bf16(af[im], bf[in], acc[im][in], 0, 0, 0);
    }
  }

  if (isXLX) {
#pragma unroll
    for (int im = 0; im < 4; ++im)
#pragma unroll
      for (int in = 0; in < 4; ++in) {
        int gr = row0 + wm * 64 + im * 16 + q * 4;
        int gc = col0 + wn * 64 + in * 16 + n16;
#pragma unroll
        for (int tt = 0; tt < 4; ++tt)
          atomicAdd(&prec[(size_t)(gr + tt) * NFF + gc], acc[im][in][tt]);
      }
  } else {
#pragma unroll
    for (int im = 0; im < 4; ++im)
#pragma unroll
      for (int in = 0; in < 4; ++in) {
        int gr = row0 + wm * 64 + im * 16 + q * 4;
        int gc = wn * 64 + in * 16 + n16;
#pragma unroll
        for (int tt = 0; tt < 4; ++tt)
          atomicAdd(&XLY[(size_t)(gr + tt) * NCO + gc], acc[im][in][tt]);
      }
  }
}

// ---------------------------------------------------------------- Cholesky NB=64, single-wave diag
__global__ __launch_bounds__(64) void k_chol_diag(float* __restrict__ P, int p) {
  int s = blockIdx.x;
  float* Ps = P + (size_t)s * NFF * NFF + (size_t)(p * 64) * NFF + p * 64;
  __shared__ float D[64][65];
  int t = threadIdx.x;
  // load 64x64 (float4 per lane per iter)
  for (int e = t; e < 1024; e += 64) {
    int r = e >> 4, cq = (e & 15) * 4;
    float4 v = *(const float4*)(Ps + (size_t)r * NFF + cq);
    D[r][cq + 0] = v.x; D[r][cq + 1] = v.y; D[r][cq + 2] = v.z; D[r][cq + 3] = v.w;
  }
  __syncthreads();
  for (int j = 0; j < 64; ++j) {
    float dj = sqrtf(D[j][j]);
    float inv = 1.0f / dj;
    float lij = 0.f;
    if (t == j) D[j][j] = dj;
    if (t > j) { lij = D[t][j] * inv; D[t][j] = lij; }
    __syncthreads();              // single wave: near-free; column j final
    for (int k = j + 1; k <= t; ++k) D[t][k] = fmaf(-lij, D[k][j], D[t][k]);
    __syncthreads();              // rank-1 visible (incl. D[j+1][j+1])
  }
  for (int e = t; e < 1024; e += 64) {
    int r = e >> 4, cq = (e & 15) * 4;
    float4 v;
    v.x = D[r][cq + 0]; v.y = D[r][cq + 1]; v.z = D[r][cq + 2]; v.w = D[r][cq + 3];
    *(float4*)(Ps + (size_t)r * NFF + cq) = v;
  }
}

// panel: L21 = A21 * L11^{-T}; one 64-row block per workgroup (64 threads); sweep is sync-free per row
__global__ __launch_bounds__(64) void k_chol_panel(float* __restrict__ P, int p) {
  int s = blockIdx.y;
  int rb = p + 1 + blockIdx.x;
  float* Ps = P + (size_t)s * NFF * NFF;
  __shared__ float L11[64][65];
  __shared__ float A2[64][65];
  int t = threadIdx.x;
  int pc = p * 64, r0 = rb * 64;
  for (int e = t; e < 4096; e += 64) {
    L11[e >> 6][e & 63] = Ps[(size_t)(pc + (e >> 6)) * NFF + pc + (e & 63)];
    A2[e >> 6][e & 63] = Ps[(size_t)(r0 + (e >> 6)) * NFF + pc + (e & 63)];
  }
  __syncthreads();
  for (int j = 0; j < 64; ++j) {
    float v = A2[t][j] / L11[j][j];
    A2[t][j] = v;
    for (int k = j + 1; k < 64; ++k) A2[t][k] = fmaf(-v, L11[k][j], A2[t][k]);
  }
  __syncthreads();
  for (int e = t; e < 4096; e += 64)
    Ps[(size_t)(r0 + (e >> 6)) * NFF + pc + (e & 63)] = A2[e >> 6][e & 63];
}

// trailing: A[bi][bj] -= L21[bi] * L21[bj]^T  (64x64 tiles, K=64, lower pairs only)
__global__ __launch_bounds__(256) void k_chol_trail(float* __restrict__ P, int p) {
  int s = blockIdx.y;
  float* Ps = P + (size_t)s * NFF * NFF;
  int idx = blockIdx.x;
  int b = 0;
  while ((b + 1) * (b + 2) / 2 <= idx) b++;
  int bi = p + 1 + b;
  int bj = p + 1 + (idx - b * (b + 1) / 2);
  int pc = p * 64;
  __shared__ float Lis[64][68];
  __shared__ float Ljs[64][68];
  int tid = threadIdx.x;
  int i0 = tid >> 2, cq = tid & 3;
#pragma unroll
  for (int it = 0; it < 4; ++it) {
    int chunk = cq + it * 4;
    float4 va = *(const float4*)&Ps[(size_t)(bi * 64 + i0) * NFF + pc + chunk * 4];
    float4 vb = *(const float4*)&Ps[(size_t)(bj * 64 + i0) * NFF + pc + chunk * 4];
    Lis[chunk * 4 + 0][i0] = va.x; Lis[chunk * 4 + 1][i0] = va.y;
    Lis[chunk * 4 + 2][i0] = va.z; Lis[chunk * 4 + 3][i0] = va.w;
    Ljs[chunk * 4 + 0][i0] = vb.x; Ljs[chunk * 4 + 1][i0] = vb.y;
    Ljs[chunk * 4 + 2][i0] = vb.z; Ljs[chunk * 4 + 3][i0] = vb.w;
  }
  __syncthreads();
  int tx = tid & 15, ty = tid >> 4;
  float acc[4][4];
#pragma unroll
  for (int i = 0; i < 4; ++i)
#pragma unroll
    for (int j = 0; j < 4; ++j) acc[i][j] = 0.f;
#pragma unroll 8
  for (int kc = 0; kc < 64; ++kc) {
    float av[4], bv[4];
    *(float4*)av = *(const float4*)&Lis[kc][ty * 4];
    *(float4*)bv = *(const float4*)&Ljs[kc][tx * 4];
#pragma unroll
    for (int i = 0; i < 4; ++i)
#pragma unroll
      for (int j = 0; j < 4; ++j) acc[i][j] = fmaf(av[i], bv[j], acc[i][j]);
  }
#pragma unroll
  for (int i = 0; i < 4; ++i) {
    float4* cp = (float4*)&Ps[(size_t)(bi * 64 + ty * 4 + i) * NFF + bj * 64 + tx * 4];
    float4 cv = *cp;
    cv.x -= acc[i][0]; cv.y -= acc[i][1]; cv.z -= acc[i][2]; cv.w -= acc[i][3];
    *cp = cv;
  }
}

// ---------------------------------------------------------------- explicit inverse W = L^{-1}
__global__ __launch_bounds__(64) void k_invdiag(const float* __restrict__ P,
                                                float* __restrict__ W) {
  int ib = blockIdx.x, s = blockIdx.y;
  const float* Ps = P + (size_t)s * NFF * NFF + (size_t)(ib * 64) * NFF + ib * 64;
  float* Ws = W + (size_t)s * NFF * NFF + (size_t)(ib * 64) * NFF + ib * 64;
  __shared__ float Lt[64][65];
  __shared__ float xc[64][66];
  int t = threadIdx.x;
  for (int e = t; e < 4096; e += 64)
    Lt[e >> 6][e & 63] = Ps[(size_t)(e >> 6) * NFF + (e & 63)];
  __syncthreads();
  for (int j = 0; j < 64; ++j) {
    float v = (j == t) ? 1.f : 0.f;
    for (int k = t; k < j; ++k) v = fmaf(-Lt[j][k], xc[k][t], v);
    xc[j][t] = v / Lt[j][j];
  }
  for (int j = 0; j < 64; ++j)
    Ws[(size_t)j * NFF + t] = (j >= t) ? xc[j][t] : 0.f;
}

// off-diagonal blocks by diagonals: W[i][j] = -W[i][i] * sum_{k=j..i-1} L[i][k] W[k][j], i=j+d
__global__ __launch_bounds__(256) void k_invoff(const float* __restrict__ P,
                                                float* __restrict__ W, int d) {
  int j = blockIdx.x, s = blockIdx.y;
  int i = j + d;
  const float* Ps = P + (size_t)s * NFF * NFF;
  float* Ws = W + (size_t)s * NFF * NFF;
  __shared__ float At[64][65];
  __shared__ float Bt[64][65];
  __shared__ float Tt[64][65];
  int t = threadIdx.x, tx = t & 15, ty = t >> 4;
  int r = t >> 2;
  float acc[4][4];
#pragma unroll
  for (int a = 0; a < 4; ++a)
#pragma unroll
    for (int b = 0; b < 4; ++b) acc[a][b] = 0.f;

  for (int kb = j; kb < i; ++kb) {
    __syncthreads();
    const float* Lp = Ps + (size_t)(i * 64) * NFF + kb * 64;
    const float* Wp = Ws + (size_t)(kb * 64) * NFF + j * 64;
#pragma unroll
    for (int it = 0; it < 4; ++it) {
      int cc = (t & 3) * 4 + it * 16;
      float4 a = *(const float4*)(Lp + (size_t)r * NFF + cc);
      float4 b = *(const float4*)(Wp + (size_t)r * NFF + cc);
      At[cc + 0][r] = a.x; At[cc + 1][r] = a.y; At[cc + 2][r] = a.z; At[cc + 3][r] = a.w;
      Bt[r][cc + 0] = b.x; Bt[r][cc + 1] = b.y; Bt[r][cc + 2] = b.z; Bt[r][cc + 3] = b.w;
    }
    __syncthreads();
#pragma unroll 8
    for (int kk = 0; kk < 64; ++kk) {
      float av[4], bv[4];
#pragma unroll
      for (int a = 0; a < 4; ++a) av[a] = At[kk][ty * 4 + a];
#pragma unroll
      for (int b = 0; b < 4; ++b) bv[b] = Bt[kk][tx * 4 + b];
#pragma unroll
      for (int a = 0; a < 4; ++a)
#pragma unroll
        for (int b = 0; b < 4; ++b) acc[a][b] = fmaf(av[a], bv[b], acc[a][b]);
    }
  }
  __syncthreads();
#pragma unroll
  for (int a = 0; a < 4; ++a)
#pragma unroll
    for (int b = 0; b < 4; ++b) Tt[ty * 4 + a][tx * 4 + b] = acc[a][b];
  {
    const float* Dp = Ws + (size_t)(i * 64) * NFF + i * 64;
#pragma unroll
    for (int it = 0; it < 4; ++it) {
      int cc = (t & 3) * 4 + it * 16;
      float4 a = *(const float4*)(Dp + (size_t)r * NFF + cc);
      At[cc + 0][r] = a.x; At[cc + 1][r] = a.y; At[cc + 2][r] = a.z; At[cc + 3][r] = a.w;
    }
  }
  __syncthreads();
  float acc2[4][4];
#pragma unroll
  for (int a = 0; a < 4; ++a)
#pragma unroll
    for (int b = 0; b < 4; ++b) acc2[a][b] = 0.f;
#pragma unroll 8
  for (int kk = 0; kk < 64; ++kk) {
    float av[4], bv[4];
#pragma unroll
    for (int a = 0; a < 4; ++a) av[a] = At[kk][ty * 4 + a];
#pragma unroll
    for (int b = 0; b < 4; ++b) bv[b] = Tt[kk][tx * 4 + b];
#pragma unroll
    for (int a = 0; a < 4; ++a)
#pragma unroll
      for (int b = 0; b < 4; ++b) acc2[a][b] = fmaf(av[a], bv[b], acc2[a][b]);
  }
  float* Wo = Ws + (size_t)(i * 64) * NFF + j * 64;
#pragma unroll
  for (int a = 0; a < 4; ++a)
#pragma unroll
    for (int b = 0; b < 4; ++b)
      Wo[(size_t)(ty * 4 + a) * NFF + tx * 4 + b] = -acc2[a][b];
}

// ---------------------------------------------------------------- apply: t1R = W*XLY + Z (+sumZ^2)
__global__ __launch_bounds__(256) void k_app1(const float* __restrict__ W,
                                              const float* __restrict__ XLY,
                                              const float* __restrict__ Z,
                                              float* __restrict__ t1R,
                                              float* __restrict__ accum) {
  int rb = blockIdx.x, s = blockIdx.y;
  int r0 = rb * 64;
  const float* Ws = W + (size_t)s * NFF * NFF;
  const float* Ys = XLY + (size_t)s * NFF * NCO;
  const float* Zs = Z + (size_t)s * NFF * NCO;
  float* Os = t1R + (size_t)s * NFF * NCO;
  __shared__ float As_[16][68];
  __shared__ float Bs_[16][132];
  __shared__ float red[256];
  int t = threadIdx.x, tx = t & 15, ty = t >> 4;
  float acc[4][8];
#pragma unroll
  for (int a = 0; a < 4; ++a)
#pragma unroll
    for (int b = 0; b < 8; ++b) acc[a][b] = 0.f;
  int kmax = r0 + 64;
  for (int k0 = 0; k0 < kmax; k0 += 16) {
    float4 a = *(const float4*)(Ws + (size_t)(r0 + (t >> 2)) * NFF + k0 + (t & 3) * 4);
    float4 b0 = *(const float4*)(Ys + (size_t)(k0 + (t >> 4)) * NCO + (t & 15) * 8);
    float4 b1 = *(const float4*)(Ys + (size_t)(k0 + (t >> 4)) * NCO + (t & 15) * 8 + 4);
    __syncthreads();
    As_[(t & 3) * 4 + 0][t >> 2] = a.x; As_[(t & 3) * 4 + 1][t >> 2] = a.y;
    As_[(t & 3) * 4 + 2][t >> 2] = a.z; As_[(t & 3) * 4 + 3][t >> 2] = a.w;
    *(float4*)&Bs_[t >> 4][(t & 15) * 8] = b0;
    *(float4*)&Bs_[t >> 4][(t & 15) * 8 + 4] = b1;
    __syncthreads();
#pragma unroll
    for (int kk = 0; kk < 16; ++kk) {
      float av[4], bv[8];
#pragma unroll
      for (int a2 = 0; a2 < 4; ++a2) av[a2] = As_[kk][ty * 4 + a2];
      *(float4*)&bv[0] = *(const float4*)&Bs_[kk][tx * 8];
      *(float4*)&bv[4] = *(const float4*)&Bs_[kk][tx * 8 + 4];
#pragma unroll
      for (int a2 = 0; a2 < 4; ++a2)
#pragma unroll
        for (int b2 = 0; b2 < 8; ++b2) acc[a2][b2] = fmaf(av[a2], bv[b2], acc[a2][b2]);
    }
  }
  float z2 = 0.f;
#pragma unroll
  for (int a2 = 0; a2 < 4; ++a2) {
    int row = r0 + ty * 4 + a2;
    const float* zp = Zs + (size_t)row * NCO + tx * 8;
    float* op = Os + (size_t)row * NCO + tx * 8;
    float4 z0 = *(const float4*)zp;
    float4 z1 = *(const float4*)(zp + 4);
    float4 v0, v1;
    v0.x = acc[a2][0] + z0.x; v0.y = acc[a2][1] + z0.y;
    v0.z = acc[a2][2] + z0.z; v0.w = acc[a2][3] + z0.w;
    v1.x = acc[a2][4] + z1.x; v1.y = acc[a2][5] + z1.y;
    v1.z = acc[a2][6] + z1.z; v1.w = acc[a2][7] + z1.w;
    z2 += z0.x * z0.x + z0.y * z0.y + z0.z * z0.z + z0.w * z0.w;
    z2 += z1.x * z1.x + z1.y * z1.y + z1.z * z1.z + z1.w * z1.w;
    *(float4*)op = v0;
    *(float4*)(op + 4) = v1;
  }
  __syncthreads();
  red[t] = z2;
  __syncthreads();
  for (int o = 128; o > 0; o >>= 1) {
    if (t < o) red[t] += red[t + o];
    __syncthreads();
  }
  if (t == 0) atomicAdd(&accum[s * 4 + 1], red[0]);
}

// ---------------------------------------------------------------- apply: sample = W^T * t1R (transposed store, +sum S^2)
__global__ __launch_bounds__(256) void k_app2(const float* __restrict__ W,
                                              const float* __restrict__ t1R,
                                              float* __restrict__ sout,
                                              float* __restrict__ accum) {
  int rb = blockIdx.x, s = blockIdx.y;
  int r0 = rb * 64;
  const float* Ws = W + (size_t)s * NFF * NFF;
  const float* Rs = t1R + (size_t)s * NFF * NCO;
  float* Op = sout + (size_t)s * NCO * NFF;
  __shared__ float As_[16][68];
  __shared__ float Bs_[16][132];
  __shared__ float red[256];
  int t = threadIdx.x, tx = t & 15, ty = t >> 4;
  float acc[4][8];
#pragma unroll
  for (int a = 0; a < 4; ++a)
#pragma unroll
    for (int b = 0; b < 8; ++b) acc[a][b] = 0.f;
  for (int k0 = r0; k0 < NFF; k0 += 16) {
    float4 a = *(const float4*)(Ws + (size_t)(k0 + (t >> 4)) * NFF + r0 + (t & 15) * 4);
    float4 b0 = *(const float4*)(Rs + (size_t)(k0 + (t >> 4)) * NCO + (t & 15) * 8);
    float4 b1 = *(const float4*)(Rs + (size_t)(k0 + (t >> 4)) * NCO + (t & 15) * 8 + 4);
    __syncthreads();
    *(float4*)&As_[t >> 4][(t & 15) * 4] = a;
    *(float4*)&Bs_[t >> 4][(t & 15) * 8] = b0;
    *(float4*)&Bs_[t >> 4][(t & 15) * 8 + 4] = b1;
    __syncthreads();
#pragma unroll
    for (int kk = 0; kk < 16; ++kk) {
      float av[4], bv[8];
#pragma unroll
      for (int a2 = 0; a2 < 4; ++a2) av[a2] = As_[kk][ty * 4 + a2];
      *(float4*)&bv[0] = *(const float4*)&Bs_[kk][tx * 8];
      *(float4*)&bv[4] = *(const float4*)&Bs_[kk][tx * 8 + 4];
#pragma unroll
      for (int a2 = 0; a2 < 4; ++a2)
#pragma unroll
        for (int b2 = 0; b2 < 8; ++b2) acc[a2][b2] = fmaf(av[a2], bv[b2], acc[a2][b2]);
    }
  }
  float s2 = 0.f;
#pragma unroll
  for (int b2 = 0; b2 < 8; ++b2) {
    int col = tx * 8 + b2;
    float4 v;
    v.x = acc[0][b2]; v.y = acc[1][b2]; v.z = acc[2][b2]; v.w = acc[3][b2];
    s2 += v.x * v.x + v.y * v.y + v.z * v.z + v.w * v.w;
    *(float4*)(Op + (size_t)col * NFF + r0 + ty * 4) = v;
  }
  __syncthreads();
  red[t] = s2;
  __syncthreads();
  for (int o = 128; o > 0; o >>= 1) {
    if (t < o) red[t] += red[t + o];
    __syncthreads();
  }
  if (t == 0) atomicAdd(&accum[s * 4 + 0], red[0]);
}

// ---------------------------------------------------------------- epilogue
__global__ __launch_bounds__(256) void k_logdet(const float* __restrict__ P,
                                                float* __restrict__ accum) {
  int s = blockIdx.x;
  float part = 0.f;
  for (int i = threadIdx.x; i < NFF; i += 256)
    part += logf(P[(size_t)s * NFF * NFF + (size_t)i * NFF + i]);
  __shared__ float r[256];
  r[threadIdx.x] = part;
  __syncthreads();
  for (int off = 128; off > 0; off >>= 1) {
    if (threadIdx.x < off) r[threadIdx.x] += r[threadIdx.x + off];
    __syncthreads();
  }
  if (threadIdx.x == 0) {
    accum[s * 4 + 0] = 0.f;
    accum[s * 4 + 1] = 0.f;
    accum[s * 4 + 2] = 2.f * r[0];
  }
}

__global__ void k_final(const float* __restrict__ accum, float* __restrict__ outLogpq) {
  int s = threadIdx.x;
  if (s < NS) {
    float s2 = accum[s * 4 + 0];
    float z2 = accum[s * 4 + 1];
    float ld = accum[s * 4 + 2];
    float logP = -0.5f * LAMV * s2 + 0.5f * (float)(NCO * NFF) * logf(LAMV);
    float logQ = -0.5f * z2 + 0.5f * (float)NCO * ld;
    outLogpq[s] = logP - logQ;
  }
}

// ---------------------------------------------------------------- launch
extern "C" void kernel_launch(void* const* d_in, const int* in_sizes, int n_in,
                              void* d_out, int out_size, void* d_ws, size_t ws_size,
                              hipStream_t stream) {
  const float* X = (const float*)d_in[0];
  const float* u = (const float*)d_in[1];
  const float* lp = (const float*)d_in[2];
  const float* Z = (const float*)d_in[3];
  float* out = (float*)d_out;

  const size_t XU2 = 18874368;   // 1152*8192*2 (bf16), one s
  const size_t FF4 = 5308416;    // 1152*1152*4
  const size_t FC4 = 589824;     // 1152*128*4
  const size_t FC = 147456;      // elems
  const size_t FF = 1327104;     // elems
  const size_t XSTR = 1048576;   // X elems per s

  char* ws = (char*)d_ws;
  // region0 (42.5 MB): Xu double-buffer (2 s) + Bm early; reused as W after GEMMs
  unsigned short* Xu = (unsigned short*)(ws);
  unsigned short* Bm = (unsigned short*)(ws + 2 * XU2);
  float* W = (float*)(ws);
  size_t off = 8 * FF4;
  float* prec = (float*)(ws + off); off += 8 * FF4;
  float* XLY = (float*)(ws + off);  off += 8 * FC4;
  float* t1R = (float*)(ws + off);  off += 8 * FC4;
  float* accum = (float*)(ws + off);

  k_build_B<<<4096, 256, 0, stream>>>(u, lp, Bm);
  hipMemsetAsync(prec, 0, 8 * FF4, stream);
  hipMemsetAsync(XLY, 0, 8 * FC4, stream);
  k_diag_init<<<dim3(5, 8), 256, 0, stream>>>(prec);

  for (int pr = 0; pr < 4; ++pr) {
    k_build_Xu<<<dim3(36864, 2), 256, 0, stream>>>(X + (size_t)pr * 2 * XSTR, lp, Xu);
    k_mfma<<<dim3(54, 8, 2), 256, 0, stream>>>(Xu, Bm,
                                               prec + (size_t)pr * 2 * FF,
                                               XLY + (size_t)pr * 2 * FC);
  }

  for (int p = 0; p < 18; ++p) {
    k_chol_diag<<<8, 64, 0, stream>>>(prec, p);
    if (p < 17) {
      int T = 17 - p;
      k_chol_panel<<<dim3(T, 8), 64, 0, stream>>>(prec, p);
      k_chol_trail<<<dim3(T * (T + 1) / 2, 8), 256, 0, stream>>>(prec, p);
    }
  }

  k_logdet<<<8, 256, 0, stream>>>(prec, accum);

  // explicit inverse W = L^{-1} (writes every block the apply kernels read)
  k_invdiag<<<dim3(18, 8), 64, 0, stream>>>(prec, W);
  for (int d = 1; d < 18; ++d)
    k_invoff<<<dim3(18 - d, 8), 256, 0, stream>>>(prec, W, d);

  // sample = W^T (W XLY + Z); fused reductions
  k_app1<<<dim3(18, 8), 256, 0, stream>>>(W, XLY, Z, t1R, accum);
  k_app2<<<dim3(18, 8), 256, 0, stream>>>(W, t1R, out, accum);
  k_final<<<1, 64, 0, stream>>>(accum, out + (size_t)NS * FC);
}

// Round 6
// 3377.438 us; speedup vs baseline: 5.0253x; 1.1143x over previous
//
#include <hip/hip_runtime.h>
#include <hip/hip_bf16.h>
#include <math.h>

#define NS    8
#define NNI   32
#define NCI   128
#define NHH   16
#define NWW   16
#define NCO   128
#define NFF   1152
#define NLL   256
#define LAMV  1152.0f

typedef short s8v __attribute__((ext_vector_type(8)));
typedef float f4v __attribute__((ext_vector_type(4)));

#define AS1 __attribute__((address_space(1)))
#define AS3 __attribute__((address_space(3)))

// ---------------------------------------------------------------- build Xu (bf16), two s per launch
__global__ __launch_bounds__(256) void k_build_Xu(const float* __restrict__ X,
                                                  const float* __restrict__ lp,
                                                  unsigned short* __restrict__ Xu) {
  unsigned z = blockIdx.y;
  unsigned idx = blockIdx.x * 256u + threadIdx.x;   // < 1152*8192
  unsigned m = idx & 8191u;
  unsigned f = idx >> 13;
  unsigned n = m >> 8, l = m & 255u, h = l >> 4, w = l & 15u;
  unsigned c = f / 9u, a = f - 9u * c;
  unsigned ki = a / 3u, kj = a - 3u * ki;
  int hi = (int)(h + ki) - 1, wi = (int)(w + kj) - 1;
  float v = 0.f;
  if (hi >= 0 && hi < NHH && wi >= 0 && wi < NWW)
    v = X[(size_t)z * 1048576 + (((size_t)n * NCI + c) << 8) + (unsigned)(hi * NWW + wi)];
  float sp = expf(0.5f * lp[n]);
  __hip_bfloat16 hv = __float2bfloat16(sp * v);
  Xu[(size_t)z * (NFF * 8192) + idx] = *(unsigned short*)&hv;
}

__global__ __launch_bounds__(256) void k_build_B(const float* __restrict__ u,
                                                 const float* __restrict__ lp,
                                                 unsigned short* __restrict__ Bm) {
  unsigned idx = blockIdx.x * 256u + threadIdx.x;   // < 1,048,576
  unsigned m = idx & 8191u;
  unsigned c = idx >> 13;
  unsigned n = m >> 8, l = m & 255u;
  float sp = expf(0.5f * lp[n]);
  __hip_bfloat16 hv = __float2bfloat16(sp * u[((size_t)n * NCO + c) * NLL + l]);
  Bm[idx] = *(unsigned short*)&hv;
}

__global__ void k_diag_init(float* __restrict__ prec) {
  int s = blockIdx.y;
  int i = blockIdx.x * 256 + threadIdx.x;
  if (i < NFF) prec[(size_t)s * NFF * NFF + (size_t)i * NFF + i] = LAMV;
}

// ---------------------------------------------------------------- MFMA bf16 GEMM, two s per launch, K-split 4
__global__ __launch_bounds__(256) void k_mfma(const unsigned short* __restrict__ XuBase,
                                              const unsigned short* __restrict__ Bm,
                                              float* __restrict__ prec,
                                              float* __restrict__ XLY) {
  __shared__ unsigned short As[8192];
  __shared__ unsigned short Bs[8192];
  int z = blockIdx.z;
  const unsigned short* Xu = XuBase + (size_t)z * (NFF * 8192);
  prec += (size_t)z * NFF * NFF;
  XLY += (size_t)z * NFF * NCO;
  int bx = blockIdx.x;
  int row0, col0;
  const unsigned short* Ag;
  const unsigned short* Bg;
  bool isXLX;
  if (bx < 45) {
    int b = 0;
    while ((b + 1) * (b + 2) / 2 <= bx) b++;
    row0 = b * 128;
    col0 = (bx - b * (b + 1) / 2) * 128;
    Bg = Xu + (size_t)col0 * 8192;
    isXLX = true;
  } else {
    row0 = (bx - 45) * 128;
    col0 = 0;
    Bg = Bm;
    isXLX = false;
  }
  Ag = Xu + (size_t)row0 * 8192;

  int t = threadIdx.x;
  int lane = t & 63, w = t >> 6;
  int wm = w & 1, wn = w >> 1;
  int n16 = lane & 15, q = lane >> 4;
  int srow = lane >> 3, sch = lane & 7;

  f4v acc[4][4];
#pragma unroll
  for (int i = 0; i < 4; ++i)
#pragma unroll
    for (int j = 0; j < 4; ++j) acc[i][j] = (f4v)0.f;

  int kBase = blockIdx.y * 2048;
  for (int k0 = kBase; k0 < kBase + 2048; k0 += 64) {
    __syncthreads();
#pragma unroll
    for (int it = 0; it < 4; ++it) {
      int rA = (w * 4 + it) * 8 + srow;
      int cA = (sch - rA) & 7;
      const unsigned short* gpa = Ag + (size_t)rA * 8192 + k0 + cA * 8;
      const unsigned short* gpb = Bg + (size_t)rA * 8192 + k0 + cA * 8;
      __builtin_amdgcn_global_load_lds((AS1 const void*)gpa,
                                       (AS3 void*)&As[(w * 4 + it) * 512], 16, 0, 0);
      __builtin_amdgcn_global_load_lds((AS1 const void*)gpb,
                                       (AS3 void*)&Bs[(w * 4 + it) * 512], 16, 0, 0);
    }
    __syncthreads();
#pragma unroll
    for (int kk = 0; kk < 2; ++kk) {
      s8v af[4], bf[4];
#pragma unroll
      for (int im = 0; im < 4; ++im) {
        int r = wm * 64 + im * 16 + n16;
        int slot = ((kk * 4 + q) + r) & 7;
        af[im] = *(const s8v*)&As[r * 64 + slot * 8];
      }
#pragma unroll
      for (int in = 0; in < 4; ++in) {
        int r = wn * 64 + in * 16 + n16;
        int slot = ((kk * 4 + q) + r) & 7;
        bf[in] = *(const s8v*)&Bs[r * 64 + slot * 8];
      }
#pragma unroll
      for (int im = 0; im < 4; ++im)
#pragma unroll
        for (int in = 0; in < 4; ++in)
          acc[im][in] = __builtin_amdgcn_mfma_f32_16x16x32_bf16(af[im], bf[in], acc[im][in], 0, 0, 0);
    }
  }

  if (isXLX) {
#pragma unroll
    for (int im = 0; im < 4; ++im)
#pragma unroll
      for (int in = 0; in < 4; ++in) {
        int gr = row0 + wm * 64 + im * 16 + q * 4;
        int gc = col0 + wn * 64 + in * 16 + n16;
#pragma unroll
        for (int tt = 0; tt < 4; ++tt)
          atomicAdd(&prec[(size_t)(gr + tt) * NFF + gc], acc[im][in][tt]);
      }
  } else {
#pragma unroll
    for (int im = 0; im < 4; ++im)
#pragma unroll
      for (int in = 0; in < 4; ++in) {
        int gr = row0 + wm * 64 + im * 16 + q * 4;
        int gc = wn * 64 + in * 16 + n16;
#pragma unroll
        for (int tt = 0; tt < 4; ++tt)
          atomicAdd(&XLY[(size_t)(gr + tt) * NCO + gc], acc[im][in][tt]);
      }
  }
}

// ---------------------------------------------------------------- Cholesky: diag for p=0 (single wave)
__global__ __launch_bounds__(64) void k_chol_diag(float* __restrict__ P, int p) {
  int s = blockIdx.x;
  float* Ps = P + (size_t)s * NFF * NFF + (size_t)(p * 64) * NFF + p * 64;
  __shared__ float D[64][65];
  int t = threadIdx.x;
  for (int e = t; e < 1024; e += 64) {
    int r = e >> 4, cq = (e & 15) * 4;
    float4 v = *(const float4*)(Ps + (size_t)r * NFF + cq);
    D[r][cq + 0] = v.x; D[r][cq + 1] = v.y; D[r][cq + 2] = v.z; D[r][cq + 3] = v.w;
  }
  __syncthreads();
  for (int j = 0; j < 64; ++j) {
    float dj = sqrtf(D[j][j]);
    float inv = 1.0f / dj;
    float lij = 0.f;
    if (t == j) D[j][j] = dj;
    if (t > j) { lij = D[t][j] * inv; D[t][j] = lij; }
    __syncthreads();
    for (int k = j + 1; k <= t; ++k) D[t][k] = fmaf(-lij, D[k][j], D[t][k]);
    __syncthreads();
  }
  for (int e = t; e < 1024; e += 64) {
    int r = e >> 4, cq = (e & 15) * 4;
    float4 v;
    v.x = D[r][cq + 0]; v.y = D[r][cq + 1]; v.z = D[r][cq + 2]; v.w = D[r][cq + 3];
    *(float4*)(Ps + (size_t)r * NFF + cq) = v;
  }
}

// ---------------------------------------------------------------- fused chol step p:
// per trail tile (bi,bj): re-TRSM rows bi (wave0) & bj (wave1) in LDS, rank-update.
// Diagonal tiles (b==c) write TRSM panel TRANSPOSED into the (unused) upper
// triangle (row pc+cc, col bi*64+r) -> no race with other tiles' pre-TRSM reads.
// Tile idx0 additionally factors the updated (p+1,p+1) diag in-LDS.
__global__ __launch_bounds__(256) void k_chol_step(float* __restrict__ P, int p) {
  int s = blockIdx.y;
  float* Ps = P + (size_t)s * NFF * NFF;
  int idx = blockIdx.x;
  int b = 0;
  while ((b + 1) * (b + 2) / 2 <= idx) b++;
  int c = idx - b * (b + 1) / 2;
  int bi = p + 1 + b, bj = p + 1 + c;
  int pc = p * 64;
  __shared__ float Ld[64][65];
  __shared__ float Ai[64][65];
  __shared__ float Aj[64][65];
  int t = threadIdx.x;
  int w = t >> 6, lane = t & 63;
  for (int e = t; e < 4096; e += 256) {
    int r = e >> 6, cc = e & 63;
    Ld[r][cc] = Ps[(size_t)(pc + r) * NFF + pc + cc];
    Ai[r][cc] = Ps[(size_t)(bi * 64 + r) * NFF + pc + cc];
  }
  if (c < b)
    for (int e = t; e < 4096; e += 256) {
      int r = e >> 6, cc = e & 63;
      Aj[r][cc] = Ps[(size_t)(bj * 64 + r) * NFF + pc + cc];
    }
  __syncthreads();
  // local TRSM vs Ld (sync-free per-row sweeps, one wave each)
  if (w == 0) {
    for (int j = 0; j < 64; ++j) {
      float v = Ai[lane][j] / Ld[j][j];
      Ai[lane][j] = v;
      for (int k = j + 1; k < 64; ++k) Ai[lane][k] = fmaf(-v, Ld[k][j], Ai[lane][k]);
    }
  } else if (w == 1 && c < b) {
    for (int j = 0; j < 64; ++j) {
      float v = Aj[lane][j] / Ld[j][j];
      Aj[lane][j] = v;
      for (int k = j + 1; k < 64; ++k) Aj[lane][k] = fmaf(-v, Ld[k][j], Aj[lane][k]);
    }
  }
  __syncthreads();
  int tx = t & 15, ty = t >> 4;
  if (c == b) {
    // panel writeback, transposed into upper triangle
    for (int e = t; e < 4096; e += 256) {
      int r = e >> 6, cc = e & 63;
      Ps[(size_t)(pc + cc) * NFF + bi * 64 + r] = Ai[r][cc];
    }
    float acc[4][4];
#pragma unroll
    for (int a = 0; a < 4; ++a)
#pragma unroll
      for (int b2 = 0; b2 < 4; ++b2) acc[a][b2] = 0.f;
#pragma unroll 8
    for (int kc = 0; kc < 64; ++kc) {
      float av[4], bv[4];
#pragma unroll
      for (int a = 0; a < 4; ++a) av[a] = Ai[ty * 4 + a][kc];
#pragma unroll
      for (int b2 = 0; b2 < 4; ++b2) bv[b2] = Ai[tx * 4 + b2][kc];
#pragma unroll
      for (int a = 0; a < 4; ++a)
#pragma unroll
        for (int b2 = 0; b2 < 4; ++b2) acc[a][b2] = fmaf(av[a], bv[b2], acc[a][b2]);
    }
    if (b == 0) {
      // updated next diag into Aj, factor, write canonical
      __syncthreads();
#pragma unroll
      for (int a = 0; a < 4; ++a) {
        float4 g = *(const float4*)&Ps[(size_t)(bi * 64 + ty * 4 + a) * NFF + bi * 64 + tx * 4];
        Aj[ty * 4 + a][tx * 4 + 0] = g.x - acc[a][0];
        Aj[ty * 4 + a][tx * 4 + 1] = g.y - acc[a][1];
        Aj[ty * 4 + a][tx * 4 + 2] = g.z - acc[a][2];
        Aj[ty * 4 + a][tx * 4 + 3] = g.w - acc[a][3];
      }
      __syncthreads();
      for (int j = 0; j < 64; ++j) {
        if (w == 0) {
          float dj = sqrtf(Aj[j][j]);
          float inv = 1.0f / dj;
          float lij = 0.f;
          if (lane == j) Aj[j][j] = dj;
          if (lane > j) { lij = Aj[lane][j] * inv; Aj[lane][j] = lij; }
          for (int k = j + 1; k <= lane; ++k) Aj[lane][k] = fmaf(-lij, Aj[k][j], Aj[lane][k]);
        }
        __syncthreads();
      }
      for (int e = t; e < 4096; e += 256) {
        int r = e >> 6, cc = e & 63;
        Ps[(size_t)(bi * 64 + r) * NFF + bi * 64 + cc] = Aj[r][cc];
      }
    } else {
#pragma unroll
      for (int a = 0; a < 4; ++a) {
        float4* cp = (float4*)&Ps[(size_t)(bi * 64 + ty * 4 + a) * NFF + bi * 64 + tx * 4];
        float4 cv = *cp;
        cv.x -= acc[a][0]; cv.y -= acc[a][1]; cv.z -= acc[a][2]; cv.w -= acc[a][3];
        *cp = cv;
      }
    }
  } else {
    float acc[4][4];
#pragma unroll
    for (int a = 0; a < 4; ++a)
#pragma unroll
      for (int b2 = 0; b2 < 4; ++b2) acc[a][b2] = 0.f;
#pragma unroll 8
    for (int kc = 0; kc < 64; ++kc) {
      float av[4], bv[4];
#pragma unroll
      for (int a = 0; a < 4; ++a) av[a] = Ai[ty * 4 + a][kc];
#pragma unroll
      for (int b2 = 0; b2 < 4; ++b2) bv[b2] = Aj[tx * 4 + b2][kc];
#pragma unroll
      for (int a = 0; a < 4; ++a)
#pragma unroll
        for (int b2 = 0; b2 < 4; ++b2) acc[a][b2] = fmaf(av[a], bv[b2], acc[a][b2]);
    }
#pragma unroll
    for (int a = 0; a < 4; ++a) {
      float4* cp = (float4*)&Ps[(size_t)(bi * 64 + ty * 4 + a) * NFF + bj * 64 + tx * 4];
      float4 cv = *cp;
      cv.x -= acc[a][0]; cv.y -= acc[a][1]; cv.z -= acc[a][2]; cv.w -= acc[a][3];
      *cp = cv;
    }
  }
}

// ---------------------------------------------------------------- inverse diag blocks + logdet
__global__ __launch_bounds__(64) void k_invdiag(const float* __restrict__ P,
                                                float* __restrict__ W,
                                                float* __restrict__ accum) {
  int ib = blockIdx.x, s = blockIdx.y;
  const float* Ps = P + (size_t)s * NFF * NFF + (size_t)(ib * 64) * NFF + ib * 64;
  float* Ws = W + (size_t)s * NFF * NFF + (size_t)(ib * 64) * NFF + ib * 64;
  __shared__ float Lt[64][65];
  __shared__ float xc[64][66];
  int t = threadIdx.x;
  for (int e = t; e < 4096; e += 64)
    Lt[e >> 6][e & 63] = Ps[(size_t)(e >> 6) * NFF + (e & 63)];
  __syncthreads();
  float lg = logf(Lt[t][t]);
#pragma unroll
  for (int o = 32; o; o >>= 1) lg += __shfl_down(lg, o, 64);
  if (t == 0) atomicAdd(&accum[s * 4 + 2], 2.f * lg);
  for (int j = 0; j < 64; ++j) {
    float v = (j == t) ? 1.f : 0.f;
    for (int k = t; k < j; ++k) v = fmaf(-Lt[j][k], xc[k][t], v);
    xc[j][t] = v / Lt[j][j];
  }
  for (int j = 0; j < 64; ++j)
    Ws[(size_t)j * NFF + t] = (j >= t) ? xc[j][t] : 0.f;
}

// ---------------------------------------------------------------- inverse column walker
// block = (column j, col-half h, s). Serially computes W[i][j] (its 32-col half)
// for i=j+1..17: S = sum_k L[i][k] W[k][j] (L read from transposed-upper copy,
// W self-written earlier); W[i][j] = -W[i][i] * S (W[i][i] from k_invdiag).
__global__ __launch_bounds__(256) void k_invcol(const float* __restrict__ P,
                                                float* __restrict__ W) {
  int j = blockIdx.x, h = blockIdx.y, s = blockIdx.z;
  const float* Ps = P + (size_t)s * NFF * NFF;
  float* Ws = W + (size_t)s * NFF * NFF;
  int c0 = j * 64 + h * 32;
  __shared__ float Lk[64][65];   // Lk[q][r] = L[i][kb][r][q]
  __shared__ float Bt[64][33];   // W[kb][j] half
  __shared__ float Ss[64][33];   // S half
  __shared__ float Wt[64][65];   // W[i][i] transposed
  int t = threadIdx.x, tx = t & 15, ty = t >> 4;
  for (int i = j + 1; i < 18; ++i) {
    float acc[4][2];
#pragma unroll
    for (int a = 0; a < 4; ++a) { acc[a][0] = 0.f; acc[a][1] = 0.f; }
    for (int kb = j; kb < i; ++kb) {
      __syncthreads();
#pragma unroll
      for (int it = 0; it < 4; ++it) {
        int q = t >> 2;
        int r0 = (t & 3) * 4 + it * 16;
        *(float4*)&Lk[q][r0] = *(const float4*)&Ps[(size_t)(kb * 64 + q) * NFF + i * 64 + r0];
      }
#pragma unroll
      for (int it = 0; it < 2; ++it) {
        int q = t >> 2;
        int cq = (t & 3) * 4 + it * 16;
        *(float4*)&Bt[q][cq] = *(const float4*)&Ws[(size_t)(kb * 64 + q) * NFF + c0 + cq];
      }
      __syncthreads();
#pragma unroll 8
      for (int q = 0; q < 64; ++q) {
        float av[4], bv[2];
#pragma unroll
        for (int a = 0; a < 4; ++a) av[a] = Lk[q][ty * 4 + a];
        bv[0] = Bt[q][tx * 2 + 0];
        bv[1] = Bt[q][tx * 2 + 1];
#pragma unroll
        for (int a = 0; a < 4; ++a) {
          acc[a][0] = fmaf(av[a], bv[0], acc[a][0]);
          acc[a][1] = fmaf(av[a], bv[1], acc[a][1]);
        }
      }
    }
    __syncthreads();
#pragma unroll
    for (int a = 0; a < 4; ++a) {
      Ss[ty * 4 + a][tx * 2 + 0] = acc[a][0];
      Ss[ty * 4 + a][tx * 2 + 1] = acc[a][1];
    }
#pragma unroll
    for (int it = 0; it < 4; ++it) {
      int r = t >> 2;
      int q0 = (t & 3) * 4 + it * 16;
      float4 wv = *(const float4*)&Ws[(size_t)(i * 64 + r) * NFF + i * 64 + q0];
      Wt[q0 + 0][r] = wv.x; Wt[q0 + 1][r] = wv.y;
      Wt[q0 + 2][r] = wv.z; Wt[q0 + 3][r] = wv.w;
    }
    __syncthreads();
    float acc2[4][2];
#pragma unroll
    for (int a = 0; a < 4; ++a) { acc2[a][0] = 0.f; acc2[a][1] = 0.f; }
#pragma unroll 8
    for (int q = 0; q < 64; ++q) {
      float av[4], bv[2];
#pragma unroll
      for (int a = 0; a < 4; ++a) av[a] = Wt[q][ty * 4 + a];
      bv[0] = Ss[q][tx * 2 + 0];
      bv[1] = Ss[q][tx * 2 + 1];
#pragma unroll
      for (int a = 0; a < 4; ++a) {
        acc2[a][0] = fmaf(av[a], bv[0], acc2[a][0]);
        acc2[a][1] = fmaf(av[a], bv[1], acc2[a][1]);
      }
    }
#pragma unroll
    for (int a = 0; a < 4; ++a) {
      Ws[(size_t)(i * 64 + ty * 4 + a) * NFF + c0 + tx * 2 + 0] = -acc2[a][0];
      Ws[(size_t)(i * 64 + ty * 4 + a) * NFF + c0 + tx * 2 + 1] = -acc2[a][1];
    }
  }
}

// ---------------------------------------------------------------- apply: t1R = W*XLY + Z (+sumZ^2); 64x64 tiles
__global__ __launch_bounds__(256) void k_app1(const float* __restrict__ W,
                                              const float* __restrict__ XLY,
                                              const float* __restrict__ Z,
                                              float* __restrict__ t1R,
                                              float* __restrict__ accum) {
  int rb = blockIdx.x, ch = blockIdx.y, s = blockIdx.z;
  int r0 = rb * 64, c0 = ch * 64;
  const float* Ws = W + (size_t)s * NFF * NFF;
  const float* Ys = XLY + (size_t)s * NFF * NCO;
  const float* Zs = Z + (size_t)s * NFF * NCO;
  float* Os = t1R + (size_t)s * NFF * NCO;
  __shared__ float As_[16][68];
  __shared__ float Bs_[16][68];
  __shared__ float red[256];
  int t = threadIdx.x, tx = t & 15, ty = t >> 4;
  float acc[4][4];
#pragma unroll
  for (int a = 0; a < 4; ++a)
#pragma unroll
    for (int b = 0; b < 4; ++b) acc[a][b] = 0.f;
  int kmax = r0 + 64;
  for (int k0 = 0; k0 < kmax; k0 += 16) {
    float4 a = *(const float4*)(Ws + (size_t)(r0 + (t >> 2)) * NFF + k0 + (t & 3) * 4);
    float4 bb = *(const float4*)(Ys + (size_t)(k0 + (t >> 4)) * NCO + c0 + (t & 15) * 4);
    __syncthreads();
    As_[(t & 3) * 4 + 0][t >> 2] = a.x; As_[(t & 3) * 4 + 1][t >> 2] = a.y;
    As_[(t & 3) * 4 + 2][t >> 2] = a.z; As_[(t & 3) * 4 + 3][t >> 2] = a.w;
    *(float4*)&Bs_[t >> 4][(t & 15) * 4] = bb;
    __syncthreads();
#pragma unroll
    for (int kk = 0; kk < 16; ++kk) {
      float av[4], bv[4];
#pragma unroll
      for (int a2 = 0; a2 < 4; ++a2) av[a2] = As_[kk][ty * 4 + a2];
      *(float4*)&bv[0] = *(const float4*)&Bs_[kk][tx * 4];
#pragma unroll
      for (int a2 = 0; a2 < 4; ++a2)
#pragma unroll
        for (int b2 = 0; b2 < 4; ++b2) acc[a2][b2] = fmaf(av[a2], bv[b2], acc[a2][b2]);
    }
  }
  float z2 = 0.f;
#pragma unroll
  for (int a2 = 0; a2 < 4; ++a2) {
    int row = r0 + ty * 4 + a2;
    const float* zp = Zs + (size_t)row * NCO + c0 + tx * 4;
    float* op = Os + (size_t)row * NCO + c0 + tx * 4;
    float4 z0 = *(const float4*)zp;
    float4 v0;
    v0.x = acc[a2][0] + z0.x; v0.y = acc[a2][1] + z0.y;
    v0.z = acc[a2][2] + z0.z; v0.w = acc[a2][3] + z0.w;
    z2 += z0.x * z0.x + z0.y * z0.y + z0.z * z0.z + z0.w * z0.w;
    *(float4*)op = v0;
  }
  __syncthreads();
  red[t] = z2;
  __syncthreads();
  for (int o = 128; o > 0; o >>= 1) {
    if (t < o) red[t] += red[t + o];
    __syncthreads();
  }
  if (t == 0) atomicAdd(&accum[s * 4 + 1], red[0]);
}

// ---------------------------------------------------------------- apply: sample = W^T * t1R (+sum S^2); 64x64 tiles
__global__ __launch_bounds__(256) void k_app2(const float* __restrict__ W,
                                              const float* __restrict__ t1R,
                                              float* __restrict__ sout,
                                              float* __restrict__ accum) {
  int rb = blockIdx.x, ch = blockIdx.y, s = blockIdx.z;
  int r0 = rb * 64, c0 = ch * 64;
  const float* Ws = W + (size_t)s * NFF * NFF;
  const float* Rs = t1R + (size_t)s * NFF * NCO;
  float* Op = sout + (size_t)s * NCO * NFF;
  __shared__ float As_[16][68];
  __shared__ float Bs_[16][68];
  __shared__ float red[256];
  int t = threadIdx.x, tx = t & 15, ty = t >> 4;
  float acc[4][4];
#pragma unroll
  for (int a = 0; a < 4; ++a)
#pragma unroll
    for (int b = 0; b < 4; ++b) acc[a][b] = 0.f;
  for (int k0 = r0; k0 < NFF; k0 += 16) {
    float4 a = *(const float4*)(Ws + (size_t)(k0 + (t >> 4)) * NFF + r0 + (t & 15) * 4);
    float4 bb = *(const float4*)(Rs + (size_t)(k0 + (t >> 4)) * NCO + c0 + (t & 15) * 4);
    __syncthreads();
    *(float4*)&As_[t >> 4][(t & 15) * 4] = a;
    *(float4*)&Bs_[t >> 4][(t & 15) * 4] = bb;
    __syncthreads();
#pragma unroll
    for (int kk = 0; kk < 16; ++kk) {
      float av[4], bv[4];
#pragma unroll
      for (int a2 = 0; a2 < 4; ++a2) av[a2] = As_[kk][ty * 4 + a2];
      *(float4*)&bv[0] = *(const float4*)&Bs_[kk][tx * 4];
#pragma unroll
      for (int a2 = 0; a2 < 4; ++a2)
#pragma unroll
        for (int b2 = 0; b2 < 4; ++b2) acc[a2][b2] = fmaf(av[a2], bv[b2], acc[a2][b2]);
    }
  }
  float s2 = 0.f;
#pragma unroll
  for (int b2 = 0; b2 < 4; ++b2) {
    int col = c0 + tx * 4 + b2;
    float4 v;
    v.x = acc[0][b2]; v.y = acc[1][b2]; v.z = acc[2][b2]; v.w = acc[3][b2];
    s2 += v.x * v.x + v.y * v.y + v.z * v.z + v.w * v.w;
    *(float4*)(Op + (size_t)col * NFF + r0 + ty * 4) = v;
  }
  __syncthreads();
  red[t] = s2;
  __syncthreads();
  for (int o = 128; o > 0; o >>= 1) {
    if (t < o) red[t] += red[t + o];
    __syncthreads();
  }
  if (t == 0) atomicAdd(&accum[s * 4 + 0], red[0]);
}

__global__ void k_final(const float* __restrict__ accum, float* __restrict__ outLogpq) {
  int s = threadIdx.x;
  if (s < NS) {
    float s2 = accum[s * 4 + 0];
    float z2 = accum[s * 4 + 1];
    float ld = accum[s * 4 + 2];
    float logP = -0.5f * LAMV * s2 + 0.5f * (float)(NCO * NFF) * logf(LAMV);
    float logQ = -0.5f * z2 + 0.5f * (float)NCO * ld;
    outLogpq[s] = logP - logQ;
  }
}

// ---------------------------------------------------------------- launch
extern "C" void kernel_launch(void* const* d_in, const int* in_sizes, int n_in,
                              void* d_out, int out_size, void* d_ws, size_t ws_size,
                              hipStream_t stream) {
  const float* X = (const float*)d_in[0];
  const float* u = (const float*)d_in[1];
  const float* lp = (const float*)d_in[2];
  const float* Z = (const float*)d_in[3];
  float* out = (float*)d_out;

  const size_t XU2 = 18874368;   // 1152*8192*2 (bf16), one s
  const size_t FF4 = 5308416;    // 1152*1152*4
  const size_t FC4 = 589824;     // 1152*128*4
  const size_t FC = 147456;      // elems
  const size_t FF = 1327104;     // elems
  const size_t XSTR = 1048576;   // X elems per s

  char* ws = (char*)d_ws;
  // region0 (42.5 MB): Xu double-buffer (2 s) + Bm early; reused as W after GEMMs
  unsigned short* Xu = (unsigned short*)(ws);
  unsigned short* Bm = (unsigned short*)(ws + 2 * XU2);
  float* W = (float*)(ws);
  size_t off = 8 * FF4;
  float* prec = (float*)(ws + off); off += 8 * FF4;
  float* XLY = (float*)(ws + off);  off += 8 * FC4;
  float* t1R = (float*)(ws + off);  off += 8 * FC4;
  float* accum = (float*)(ws + off);

  k_build_B<<<4096, 256, 0, stream>>>(u, lp, Bm);
  hipMemsetAsync(prec, 0, 8 * FF4, stream);
  hipMemsetAsync(XLY, 0, 8 * FC4, stream);
  hipMemsetAsync(accum, 0, 1024, stream);
  k_diag_init<<<dim3(5, 8), 256, 0, stream>>>(prec);

  for (int pr = 0; pr < 4; ++pr) {
    k_build_Xu<<<dim3(36864, 2), 256, 0, stream>>>(X + (size_t)pr * 2 * XSTR, lp, Xu);
    k_mfma<<<dim3(54, 4, 2), 256, 0, stream>>>(Xu, Bm,
                                               prec + (size_t)pr * 2 * FF,
                                               XLY + (size_t)pr * 2 * FC);
  }

  // fused Cholesky: diag(0) then 17 combined steps
  k_chol_diag<<<8, 64, 0, stream>>>(prec, 0);
  for (int p = 0; p < 17; ++p) {
    int T = 17 - p;
    k_chol_step<<<dim3(T * (T + 1) / 2, 8), 256, 0, stream>>>(prec, p);
  }

  // explicit inverse W = L^{-1}: diag blocks (+logdet), then column walkers
  k_invdiag<<<dim3(18, 8), 64, 0, stream>>>(prec, W, accum);
  k_invcol<<<dim3(17, 2, 8), 256, 0, stream>>>(prec, W);

  // sample = W^T (W XLY + Z); fused reductions
  k_app1<<<dim3(18, 2, 8), 256, 0, stream>>>(W, XLY, Z, t1R, accum);
  k_app2<<<dim3(18, 2, 8), 256, 0, stream>>>(W, t1R, out, accum);
  k_final<<<1, 64, 0, stream>>>(accum, out + (size_t)NS * FC);
}